// Round 10
// baseline (494.367 us; speedup 1.0000x reference)
//
#include <hip/hip_runtime.h>
#include <hip/hip_bf16.h>

typedef __bf16 bf16_t;
typedef __bf16 bf16x8 __attribute__((ext_vector_type(8)));
typedef __bf16 bf16x4 __attribute__((ext_vector_type(4)));
typedef float  f32x4  __attribute__((ext_vector_type(4)));

// Problem constants
#define NNODES 32768
#define NPER   128
#define NGRAPH 256
#define NEDGE  131072
#define EPERG  512
#define KKEEP  128
// gathered layer-1 row layout: [0,1280) initial branch (5 rows/graph),
// [1280, 1280+4096) learned branch (16-row stride/graph, root + <=8 srcs)
#define M1     5376
#define PLANE1 (M1 * 256)

// ---------------------------------------------------------------- weight prep
__global__ void prep_kernel(const float* __restrict__ in_w,
                            const float* __restrict__ gen_w,
                            const float* __restrict__ att_w1,
                            const float* __restrict__ rel_w,
                            const float* __restrict__ root_w,
                            const float* __restrict__ in_b,
                            const float* __restrict__ gen_b,
                            bf16_t* __restrict__ wbf,    // [2][256][768]  (in_w, gen_w) = [512][768]
                            bf16_t* __restrict__ attT,   // [2][1024][256] = [2048][256]
                            bf16_t* __restrict__ lw,     // [2][5][256][256]; layer l = [1280][256]
                            float*  __restrict__ biasws) // [512] (in_b ++ gen_b)
{
  int idx = blockIdx.x * 256 + threadIdx.x;
  if (idx < 393216) {
    int which = idx / 196608, rem = idx % 196608;
    int n = rem / 768, k = rem % 768;
    const float* w = which ? gen_w : in_w;
    wbf[idx] = (bf16_t)w[k * 256 + n];
  } else if (idx < 917504) {
    int i2 = idx - 393216;
    int half = i2 / 262144, rem = i2 % 262144;
    int n = rem / 256, k = rem % 256;
    attT[i2] = (bf16_t)att_w1[(half * 256 + k) * 1024 + n];
  } else if (idx < 1572864) {
    int i3 = idx - 917504;
    int l = i3 / 327680, rem = i3 % 327680;
    int z = rem / 65536, r2 = rem % 65536;
    int n = r2 / 256, k = r2 % 256;
    float v = (z == 0) ? root_w[(l * 256 + k) * 256 + n]
                       : rel_w[((l * 4 + (z - 1)) * 256 + k) * 256 + n];
    lw[i3] = (bf16_t)v;
  } else if (idx < 1573376) {
    int j = idx - 1572864;
    biasws[j] = (j < 256) ? in_b[j] : gen_b[j - 256];
  }
}

// ---------------------------------------------------------------- cast x -> bf16
__global__ void cast_x_kernel(const float* __restrict__ x, bf16_t* __restrict__ xb)
{
  long i = (long)blockIdx.x * 256 + threadIdx.x;   // 3,145,728 threads exactly
  const float4* xf = (const float4*)x;
  float4 a = xf[i * 2], b = xf[i * 2 + 1];
  bf16x8 v;
  v[0] = (bf16_t)a.x; v[1] = (bf16_t)a.y; v[2] = (bf16_t)a.z; v[3] = (bf16_t)a.w;
  v[4] = (bf16_t)b.x; v[5] = (bf16_t)b.y; v[6] = (bf16_t)b.z; v[7] = (bf16_t)b.w;
  ((bf16x8*)xb)[i] = v;
}

// ---------------------------------------------------------------- bf16 MFMA GEMM (8-wave)
// C = act(A[M,K] @ BT[Ntot,K]^T + bias), BM=128, BN=256, BK=64, 8 waves (2x4),
// global_load_lds + XOR-swizzle (inverse-swizzled source, swizzled ds_read).
// Output columns are slab-decomposed: ncols = 1<<colShift per slab;
// C[slab*slabStride + row*ncols + (col & (ncols-1))], slab = col>>colShift.
// bias (if any) indexed by global col. Grid: (M/128, Ntot/256).
template<int ACT, bool HAS_BIAS, typename OUT_T>
__global__ __launch_bounds__(512, 1) void gemm_bt2(
    const bf16_t* __restrict__ A, const bf16_t* __restrict__ BT,
    const float* __restrict__ bias, OUT_T* __restrict__ C,
    int M, int K, int colShift, long slabStride)
{
  __shared__ bf16_t sA[8192];    // 128 rows x 64 k (16 KB)
  __shared__ bf16_t sB[16384];   // 256 rows x 64 k (32 KB)
  const int tid = threadIdx.x;
  const int lane = tid & 63, wid = tid >> 6;
  const int wr = wid >> 2, wc = wid & 3;        // 2x4 wave grid
  const long row0 = (long)blockIdx.x * 128;
  const long n0  = (long)blockIdx.y * 256;

  f32x4 acc[4][4];
  #pragma unroll
  for (int m = 0; m < 4; ++m)
    #pragma unroll
    for (int n = 0; n < 4; ++n)
      #pragma unroll
      for (int j = 0; j < 4; ++j) acc[m][n][j] = 0.f;

  for (int kt = 0; kt < K; kt += 64) {
    // stage A (2 passes of 8192 B) and B (4 passes)
    #pragma unroll
    for (int p = 0; p < 2; ++p) {
      const int P = p * 8192 + tid * 16;           // LDS byte offset (linear)
      const int row = P >> 7;
      const int cch = ((P >> 4) & 7) ^ (row & 7);  // inverse-swizzled source chunk
      const bf16_t* ga = A + (row0 + row) * (long)K + kt + cch * 8;
      bf16_t* la = sA + p * 4096 + wid * 512;      // wave-uniform base; HW adds lane*16B
      __builtin_amdgcn_global_load_lds((__attribute__((address_space(1))) void*)ga,
                                       (__attribute__((address_space(3))) void*)la, 16, 0, 0);
    }
    #pragma unroll
    for (int q = 0; q < 4; ++q) {
      const int P = q * 8192 + tid * 16;
      const int row = P >> 7;                      // 0..255
      const int cch = ((P >> 4) & 7) ^ (row & 7);
      const bf16_t* gb = BT + (n0 + row) * (long)K + kt + cch * 8;
      bf16_t* lb = sB + q * 4096 + wid * 512;
      __builtin_amdgcn_global_load_lds((__attribute__((address_space(1))) void*)gb,
                                       (__attribute__((address_space(3))) void*)lb, 16, 0, 0);
    }
    __syncthreads();
    const char* cA = (const char*)sA;
    const char* cB = (const char*)sB;
    #pragma unroll
    for (int kk = 0; kk < 2; ++kk) {
      bf16x8 af[4], bfr[4];
      #pragma unroll
      for (int m = 0; m < 4; ++m) {
        const int row = wr * 64 + m * 16 + (lane & 15);
        const int inb = (((lane >> 4) * 16) + kk * 64) ^ ((row & 7) << 4);
        af[m] = *(const bf16x8*)(cA + row * 128 + inb);
      }
      #pragma unroll
      for (int n = 0; n < 4; ++n) {
        const int row = wc * 64 + n * 16 + (lane & 15);
        const int inb = (((lane >> 4) * 16) + kk * 64) ^ ((row & 7) << 4);
        bfr[n] = *(const bf16x8*)(cB + row * 128 + inb);
      }
      #pragma unroll
      for (int m = 0; m < 4; ++m)
        #pragma unroll
        for (int n = 0; n < 4; ++n)
          acc[m][n] = __builtin_amdgcn_mfma_f32_16x16x32_bf16(af[m], bfr[n], acc[m][n], 0, 0, 0);
    }
    __syncthreads();
  }
  // epilogue: C/D layout col=lane&15, row=(lane>>4)*4+j; slab-decomposed store
  const int ncolsM1 = (1 << colShift) - 1;
  #pragma unroll
  for (int n = 0; n < 4; ++n) {
    const int col = (int)n0 + wc * 64 + n * 16 + (lane & 15);
    const int slab = col >> colShift;
    const int cin = col & ncolsM1;
    float bv = 0.f;
    if (HAS_BIAS) bv = bias[col];
    #pragma unroll
    for (int m = 0; m < 4; ++m) {
      #pragma unroll
      for (int j = 0; j < 4; ++j) {
        const long row = row0 + wr * 64 + m * 16 + (lane >> 4) * 4 + j;
        float v = acc[m][n][j] + bv;
        if (ACT == 1) v = (v > 0.f) ? v : 0.01f * v;
        C[(long)slab * slabStride + (row << colShift) + cin] = (OUT_T)v;
      }
    }
  }
}

// ---------------------------------------------------------------- edge scores
__global__ void score_kernel(const bf16_t* __restrict__ Abuf, const bf16_t* __restrict__ Bbuf,
                             const int* __restrict__ src, const int* __restrict__ dst,
                             const float* __restrict__ b1, const float* __restrict__ w2,
                             const float* __restrict__ b2, float* __restrict__ scores)
{
  __shared__ float sb1[1024], sw2[1024];
  for (int i = threadIdx.x; i < 1024; i += 256) { sb1[i] = b1[i]; sw2[i] = w2[i]; }
  __syncthreads();
  const int wid = threadIdx.x >> 6, lane = threadIdx.x & 63;
  const int e = blockIdx.x * 4 + wid;
  const int s = src[e], d = dst[e];
  const bf16x8* ar = (const bf16x8*)(Abuf + (long)s * 1024);
  const bf16x8* br = (const bf16x8*)(Bbuf + (long)d * 1024);
  float acc = 0.f;
  #pragma unroll
  for (int half = 0; half < 2; ++half) {
    bf16x8 av = ar[lane * 2 + half];
    bf16x8 bv = br[lane * 2 + half];
    const int jb = (lane * 2 + half) * 8;
    #pragma unroll
    for (int j = 0; j < 8; ++j) {
      float v = (float)av[j] + (float)bv[j] + sb1[jb + j];
      v = v > 0.f ? v : 0.f;
      acc += v * sw2[jb + j];
    }
  }
  #pragma unroll
  for (int off = 32; off > 0; off >>= 1) acc += __shfl_down(acc, off);
  if (lane == 0) scores[e] = acc + b2[0];
}

// ---------------------------------------------------------------- per-graph top-k
__global__ void topk_kernel(const float* __restrict__ scores,
                            const int* __restrict__ src, const int* __restrict__ dst,
                            const int* __restrict__ et,
                            int* __restrict__ ksrc, int* __restrict__ kdst, int* __restrict__ ktyp)
{
  const int g = blockIdx.x;
  __shared__ float sc[512];
  __shared__ int   id[512];
  for (int i = threadIdx.x; i < 512; i += 256) { sc[i] = scores[g * 512 + i]; id[i] = i; }
  for (int k2 = 2; k2 <= 512; k2 <<= 1) {
    for (int j = k2 >> 1; j > 0; j >>= 1) {
      __syncthreads();
      for (int t = threadIdx.x; t < 512; t += 256) {
        const int p = t ^ j;
        if (p > t) {
          float s1 = sc[t], s2 = sc[p];
          int   i1 = id[t], i2 = id[p];
          bool kgt = (s1 < s2) || (s1 == s2 && i1 > i2);
          bool up  = ((t & k2) == 0);
          if (kgt == up) { sc[t] = s2; sc[p] = s1; id[t] = i2; id[p] = i1; }
        }
      }
    }
  }
  __syncthreads();
  if (threadIdx.x < 128) {
    const int e = g * 512 + id[threadIdx.x];
    const int o = g * 128 + threadIdx.x;
    ksrc[o] = src[e]; kdst[o] = dst[e]; ktyp[o] = et[e];
  }
}

// ---------------------------------------------------------------- CSR build
__global__ void csr_count(const int* __restrict__ ksrc, const int* __restrict__ kdst,
                          int* __restrict__ counts)
{
  const int i = blockIdx.x * 256 + threadIdx.x;
  if (i >= NGRAPH * KKEEP) return;
  atomicAdd(&counts[kdst[i]], 1);
  atomicAdd(&counts[ksrc[i]], 1);
}

__global__ void csr_offsets(const int* __restrict__ counts, int* __restrict__ offs,
                            int* __restrict__ cursor)
{
  const int g = blockIdx.x, t = threadIdx.x;   // 128 threads
  __shared__ int s[128];
  const int mc = counts[g * 128 + t];
  s[t] = mc;
  __syncthreads();
  for (int dd = 1; dd < 128; dd <<= 1) {
    int v = (t >= dd) ? s[t - dd] : 0;
    __syncthreads();
    s[t] += v;
    __syncthreads();
  }
  const int o = g * 256 + (s[t] - mc);
  offs[g * 128 + t] = o;
  cursor[g * 128 + t] = o;
}

__global__ void csr_fill(const int* __restrict__ ksrc, const int* __restrict__ kdst,
                         const int* __restrict__ ktyp, int* __restrict__ cursor,
                         int* __restrict__ nsrc, int* __restrict__ ntyp)
{
  const int i = blockIdx.x * 256 + threadIdx.x;
  if (i >= NGRAPH * KKEEP) return;
  const int s = ksrc[i], d = kdst[i], t = ktyp[i];
  int p = atomicAdd(&cursor[d], 1); nsrc[p] = s; ntyp[p] = t;
  int q = atomicAdd(&cursor[s], 1); nsrc[q] = d; ntyp[q] = t;
}

// ---------------------------------------------------------------- selected layer-0 agg
// xw0 layout: [5][NNODES][256] bf16 (z=0 root, z=1+r relation transforms).

// Initial branch (ring graph): rows g*5 + {0:node0, o:node 128-o (o=1..4)}.
__global__ void agg_struct_sel(const bf16_t* __restrict__ xw0, const int* __restrict__ et,
                               const float* __restrict__ conv_b, bf16_t* __restrict__ h1g)
{
  const int wid = threadIdx.x >> 6, lane = threadIdx.x & 63;
  const int row = blockIdx.x * 4 + wid;         // 0..1279
  const int g = row / 5, slot = row % 5;
  const int d = (slot == 0) ? 0 : (128 - slot);
  const int n = g * 128 + d;
  const int c = lane * 4;
  int rt[4], si[4];
  #pragma unroll
  for (int oo = 0; oo < 4; ++oo) {
    const int i = (d - oo - 1 + 128) & 127;
    rt[oo] = et[g * 512 + oo * 128 + i];
    si[oo] = g * 128 + i;
  }
  const float4 cb = *(const float4*)(conv_b + c);
  bf16x4 rv = *(const bf16x4*)(xw0 + (long)n * 256 + c);
  float acc[4] = { (float)rv[0] + cb.x, (float)rv[1] + cb.y,
                   (float)rv[2] + cb.z, (float)rv[3] + cb.w };
  float s0[4] = {0,0,0,0}, s1[4] = {0,0,0,0}, s2[4] = {0,0,0,0}, s3[4] = {0,0,0,0};
  int d0 = 0, d1 = 0, d2 = 0, d3 = 0;
  #pragma unroll
  for (int oo = 0; oo < 4; ++oo) {
    const int t = rt[oo];
    bf16x4 w = *(const bf16x4*)(xw0 + ((long)(t + 1) * NNODES + si[oo]) * 256 + c);
    if (t == 0)      { d0++; for (int j = 0; j < 4; ++j) s0[j] += (float)w[j]; }
    else if (t == 1) { d1++; for (int j = 0; j < 4; ++j) s1[j] += (float)w[j]; }
    else if (t == 2) { d2++; for (int j = 0; j < 4; ++j) s2[j] += (float)w[j]; }
    else             { d3++; for (int j = 0; j < 4; ++j) s3[j] += (float)w[j]; }
  }
  if (d0) { float r = 1.f / d0; for (int j = 0; j < 4; ++j) acc[j] += s0[j] * r; }
  if (d1) { float r = 1.f / d1; for (int j = 0; j < 4; ++j) acc[j] += s1[j] * r; }
  if (d2) { float r = 1.f / d2; for (int j = 0; j < 4; ++j) acc[j] += s2[j] * r; }
  if (d3) { float r = 1.f / d3; for (int j = 0; j < 4; ++j) acc[j] += s3[j] * r; }
  bf16x4 ov; for (int j = 0; j < 4; ++j) ov[j] = (bf16_t)acc[j];
  *(bf16x4*)(h1g + (long)row * 256 + c) = ov;
}

// Learned branch (CSR graph): rows 1280 + g*16 + {0:ptr, 1+j: nsrc[off0+j]}.
__global__ void agg_csr_sel(const bf16_t* __restrict__ xw0, const int* __restrict__ offs,
                            const int* __restrict__ cnts, const int* __restrict__ nsrc,
                            const int* __restrict__ ntyp, const float* __restrict__ conv_b,
                            bf16_t* __restrict__ h1g)
{
  const int wid = threadIdx.x >> 6, lane = threadIdx.x & 63;
  const int idx = blockIdx.x * 4 + wid;         // 0..4095
  const int g = idx >> 4, slot = idx & 15;
  const int off0 = offs[g * 128], cnt0 = cnts[g * 128];
  if (slot > cnt0) return;                      // slot 0 = root, 1..cnt0 = srcs
  const int v = (slot == 0) ? g * 128 : nsrc[off0 + slot - 1];
  const int row = 1280 + idx;
  const int offv = offs[v], cntv = cnts[v];
  const int c = lane * 4;
  const float4 cb = *(const float4*)(conv_b + c);
  bf16x4 rv = *(const bf16x4*)(xw0 + (long)v * 256 + c);
  float acc[4] = { (float)rv[0] + cb.x, (float)rv[1] + cb.y,
                   (float)rv[2] + cb.z, (float)rv[3] + cb.w };
  float s0[4] = {0,0,0,0}, s1[4] = {0,0,0,0}, s2[4] = {0,0,0,0}, s3[4] = {0,0,0,0};
  int d0 = 0, d1 = 0, d2 = 0, d3 = 0;
  for (int j = 0; j < cntv; ++j) {
    const int t = ntyp[offv + j];
    const int sv = nsrc[offv + j];
    bf16x4 w = *(const bf16x4*)(xw0 + ((long)(t + 1) * NNODES + sv) * 256 + c);
    if (t == 0)      { d0++; for (int q = 0; q < 4; ++q) s0[q] += (float)w[q]; }
    else if (t == 1) { d1++; for (int q = 0; q < 4; ++q) s1[q] += (float)w[q]; }
    else if (t == 2) { d2++; for (int q = 0; q < 4; ++q) s2[q] += (float)w[q]; }
    else             { d3++; for (int q = 0; q < 4; ++q) s3[q] += (float)w[q]; }
  }
  if (d0) { float r = 1.f / d0; for (int q = 0; q < 4; ++q) acc[q] += s0[q] * r; }
  if (d1) { float r = 1.f / d1; for (int q = 0; q < 4; ++q) acc[q] += s1[q] * r; }
  if (d2) { float r = 1.f / d2; for (int q = 0; q < 4; ++q) acc[q] += s2[q] * r; }
  if (d3) { float r = 1.f / d3; for (int q = 0; q < 4; ++q) acc[q] += s3[q] * r; }
  bf16x4 ov; for (int q = 0; q < 4; ++q) ov[q] = (bf16_t)acc[q];
  *(bf16x4*)(h1g + (long)row * 256 + c) = ov;
}

// ---------------------------------------------------------------- final (layer-1) agg at ptr
// xw1 layout: [5][M1][256] bf16 over the gathered rows.
__global__ void fagg_init(const bf16_t* __restrict__ xw1, const int* __restrict__ et,
                          const float* __restrict__ conv_b1, float* __restrict__ h2I)
{
  const int wid = threadIdx.x >> 6, lane = threadIdx.x & 63;
  const int g = blockIdx.x * 4 + wid;           // 0..255
  const int base = g * 5;
  const int c = lane * 4;
  const float4 cb = *(const float4*)(conv_b1 + c);
  bf16x4 rv = *(const bf16x4*)(xw1 + (long)base * 256 + c);
  float acc[4] = { (float)rv[0] + cb.x, (float)rv[1] + cb.y,
                   (float)rv[2] + cb.z, (float)rv[3] + cb.w };
  float s0[4] = {0,0,0,0}, s1[4] = {0,0,0,0}, s2[4] = {0,0,0,0}, s3[4] = {0,0,0,0};
  int d0 = 0, d1 = 0, d2 = 0, d3 = 0;
  #pragma unroll
  for (int o = 1; o <= 4; ++o) {
    const int t = et[g * 512 + (o - 1) * 128 + (128 - o)];
    bf16x4 w = *(const bf16x4*)(xw1 + ((long)(t + 1) * M1 + base + o) * 256 + c);
    if (t == 0)      { d0++; for (int q = 0; q < 4; ++q) s0[q] += (float)w[q]; }
    else if (t == 1) { d1++; for (int q = 0; q < 4; ++q) s1[q] += (float)w[q]; }
    else if (t == 2) { d2++; for (int q = 0; q < 4; ++q) s2[q] += (float)w[q]; }
    else             { d3++; for (int q = 0; q < 4; ++q) s3[q] += (float)w[q]; }
  }
  if (d0) { float r = 1.f / d0; for (int q = 0; q < 4; ++q) acc[q] += s0[q] * r; }
  if (d1) { float r = 1.f / d1; for (int q = 0; q < 4; ++q) acc[q] += s1[q] * r; }
  if (d2) { float r = 1.f / d2; for (int q = 0; q < 4; ++q) acc[q] += s2[q] * r; }
  if (d3) { float r = 1.f / d3; for (int q = 0; q < 4; ++q) acc[q] += s3[q] * r; }
  *(float4*)(h2I + (long)g * 256 + c) = make_float4(acc[0], acc[1], acc[2], acc[3]);
}

__global__ void fagg_learn(const bf16_t* __restrict__ xw1, const int* __restrict__ offs,
                           const int* __restrict__ cnts, const int* __restrict__ ntyp,
                           const float* __restrict__ conv_b1, float* __restrict__ h2L)
{
  const int wid = threadIdx.x >> 6, lane = threadIdx.x & 63;
  const int g = blockIdx.x * 4 + wid;           // 0..255
  const int base = 1280 + g * 16;
  const int off0 = offs[g * 128], cnt0 = cnts[g * 128];
  const int c = lane * 4;
  const float4 cb = *(const float4*)(conv_b1 + c);
  bf16x4 rv = *(const bf16x4*)(xw1 + (long)base * 256 + c);
  float acc[4] = { (float)rv[0] + cb.x, (float)rv[1] + cb.y,
                   (float)rv[2] + cb.z, (float)rv[3] + cb.w };
  float s0[4] = {0,0,0,0}, s1[4] = {0,0,0,0}, s2[4] = {0,0,0,0}, s3[4] = {0,0,0,0};
  int d0 = 0, d1 = 0, d2 = 0, d3 = 0;
  for (int j = 0; j < cnt0; ++j) {
    const int t = ntyp[off0 + j];
    bf16x4 w = *(const bf16x4*)(xw1 + ((long)(t + 1) * M1 + base + 1 + j) * 256 + c);
    if (t == 0)      { d0++; for (int q = 0; q < 4; ++q) s0[q] += (float)w[q]; }
    else if (t == 1) { d1++; for (int q = 0; q < 4; ++q) s1[q] += (float)w[q]; }
    else if (t == 2) { d2++; for (int q = 0; q < 4; ++q) s2[q] += (float)w[q]; }
    else             { d3++; for (int q = 0; q < 4; ++q) s3[q] += (float)w[q]; }
  }
  if (d0) { float r = 1.f / d0; for (int q = 0; q < 4; ++q) acc[q] += s0[q] * r; }
  if (d1) { float r = 1.f / d1; for (int q = 0; q < 4; ++q) acc[q] += s1[q] * r; }
  if (d2) { float r = 1.f / d2; for (int q = 0; q < 4; ++q) acc[q] += s2[q] * r; }
  if (d3) { float r = 1.f / d3; for (int q = 0; q < 4; ++q) acc[q] += s3[q] * r; }
  *(float4*)(h2L + (long)g * 256 + c) = make_float4(acc[0], acc[1], acc[2], acc[3]);
}

// ---------------------------------------------------------------- classifier head
__global__ void classifier_kernel(const float* __restrict__ h2I, const float* __restrict__ h2L,
                                  const float* __restrict__ w1, const float* __restrict__ b1,
                                  const float* __restrict__ w2, const float* __restrict__ b2,
                                  const int* __restrict__ y, float* __restrict__ out,
                                  float* __restrict__ logp)
{
  const int g = blockIdx.x, t = threadIdx.x;
  __shared__ float rep[512];
  __shared__ float hid[256];
  __shared__ float lg[4];
  rep[t] = h2I[g * 256 + t];
  rep[256 + t] = h2L[g * 256 + t];
  __syncthreads();
  float a = b1[t];
  for (int i = 0; i < 512; ++i) a += rep[i] * w1[i * 256 + t];
  hid[t] = a > 0.f ? a : 0.01f * a;
  __syncthreads();
  if (t < 4) {
    float s = b2[t];
    for (int j = 0; j < 256; ++j) s += hid[j] * w2[j * 4 + t];
    lg[t] = s;
    out[g * 4 + t] = s;
  }
  __syncthreads();
  if (t == 0) {
    float m = fmaxf(fmaxf(lg[0], lg[1]), fmaxf(lg[2], lg[3]));
    float se = expf(lg[0] - m) + expf(lg[1] - m) + expf(lg[2] - m) + expf(lg[3] - m);
    logp[g] = lg[y[g]] - (m + logf(se));
  }
}

__global__ void finalize_kernel(const float* __restrict__ logp, const int* __restrict__ y,
                                float* __restrict__ out)
{
  __shared__ float s[256];
  const int t = threadIdx.x;
  s[t] = logp[t];
  __syncthreads();
  for (int d = 128; d > 0; d >>= 1) {
    if (t < d) s[t] += s[t + d];
    __syncthreads();
  }
  if (t == 0) out[1024] = -s[0] / 256.f;
  out[1025 + t] = (float)y[t];
}

// ---------------------------------------------------------------- launcher
extern "C" void kernel_launch(void* const* d_in, const int* in_sizes, int n_in,
                              void* d_out, int out_size, void* d_ws, size_t ws_size,
                              hipStream_t stream)
{
  (void)in_sizes; (void)n_in; (void)out_size; (void)ws_size;
  const float* x      = (const float*)d_in[0];
  const int*   ei     = (const int*)d_in[1];
  const int*   et     = (const int*)d_in[2];
  const int*   y      = (const int*)d_in[3];
  const float* gen_w  = (const float*)d_in[4];
  const float* gen_b  = (const float*)d_in[5];
  const float* att_w1 = (const float*)d_in[6];
  const float* att_b1 = (const float*)d_in[7];
  const float* att_w2 = (const float*)d_in[8];
  const float* att_b2 = (const float*)d_in[9];
  const float* in_w   = (const float*)d_in[10];
  const float* in_b   = (const float*)d_in[11];
  const float* rel_w  = (const float*)d_in[12];
  const float* root_w = (const float*)d_in[13];
  const float* conv_b = (const float*)d_in[14];
  const float* cls_w1 = (const float*)d_in[15];
  const float* cls_b1 = (const float*)d_in[16];
  const float* cls_w2 = (const float*)d_in[17];
  const float* cls_b2 = (const float*)d_in[18];
  const int* src = ei;
  const int* dst = ei + NEDGE;

  char* ws = (char*)d_ws;
  // Region 0 (time-shared, sequential lifetimes):
  //   xbf (50.3MB) -> AB (134.2MB, un-chunked) -> xw0 (83.9MB); region0 = 134.2MB
  // ws_size >= 402 MB (observed poison-fill size); total usage ~190 MB.
  size_t off = 134217728;
  const size_t oBIG = 0;
  auto alloc = [&](size_t bytes) { size_t r = off; off += (bytes + 255) & ~(size_t)255; return r; };
  const size_t oH0  = alloc((size_t)NNODES * 256 * 2);
  const size_t oHG  = alloc((size_t)NNODES * 256 * 2);   // adjacent to oH0 (N-batched GEMM)
  const size_t oH1G = alloc((size_t)M1 * 256 * 2);
  const size_t oXW1 = alloc((size_t)5 * M1 * 256 * 2);
  const size_t oSC  = alloc((size_t)NEDGE * 4);
  const size_t oKS  = alloc((size_t)NGRAPH * KKEEP * 4);
  const size_t oKD  = alloc((size_t)NGRAPH * KKEEP * 4);
  const size_t oKT  = alloc((size_t)NGRAPH * KKEEP * 4);
  const size_t oCNT = alloc((size_t)NNODES * 4);
  const size_t oOFF = alloc((size_t)NNODES * 4);
  const size_t oCUR = alloc((size_t)NNODES * 4);
  const size_t oNS  = alloc((size_t)2 * NGRAPH * KKEEP * 4);
  const size_t oNT  = alloc((size_t)2 * NGRAPH * KKEEP * 4);
  const size_t oWBF = alloc((size_t)2 * 256 * 768 * 2);
  const size_t oATT = alloc((size_t)2 * 1024 * 256 * 2);
  const size_t oLW  = alloc((size_t)2 * 5 * 256 * 256 * 2);
  const size_t oBIA = alloc(512 * 4);
  const size_t oH2I = alloc((size_t)NGRAPH * 256 * 4);
  const size_t oH2L = alloc((size_t)NGRAPH * 256 * 4);
  const size_t oLP  = alloc((size_t)NGRAPH * 4);

  bf16_t* xbf  = (bf16_t*)(ws + oBIG);
  bf16_t* AB   = (bf16_t*)(ws + oBIG);   // [2][32768][1024]
  bf16_t* xw0  = (bf16_t*)(ws + oBIG);   // [5][NNODES][256]
  bf16_t* h0   = (bf16_t*)(ws + oH0);
  bf16_t* hg   = (bf16_t*)(ws + oHG);
  bf16_t* h1g  = (bf16_t*)(ws + oH1G);   // [M1][256] gathered layer-1 input
  bf16_t* xw1  = (bf16_t*)(ws + oXW1);   // [5][M1][256]
  bf16_t* wbf  = (bf16_t*)(ws + oWBF);
  bf16_t* attT = (bf16_t*)(ws + oATT);
  bf16_t* lw   = (bf16_t*)(ws + oLW);
  float*  bias = (float*)(ws + oBIA);

  // 1. weight prep + x cast
  prep_kernel<<<6146, 256, 0, stream>>>(in_w, gen_w, att_w1, rel_w, root_w, in_b, gen_b,
                                        wbf, attT, lw, bias);
  cast_x_kernel<<<12288, 256, 0, stream>>>(x, xbf);

  // 2. h0 = leaky(x@in_w+b), hg = leaky(x@gen_w+b): one GEMM, Ntot=512, slabs of 256
  gemm_bt2<1, true, bf16_t><<<dim3(256, 2), 512, 0, stream>>>(
      xbf, wbf, bias, h0, NNODES, 768, 8, 8388608L);

  // 3. A/B node factors: one GEMM, Ntot=2048, slabs of 1024; then per-edge scores
  gemm_bt2<0, false, bf16_t><<<dim3(256, 8), 512, 0, stream>>>(
      hg, attT, nullptr, AB, NNODES, 256, 10, 33554432L);
  score_kernel<<<32768, 256, 0, stream>>>(AB, AB + 33554432L, src, dst, att_b1, att_w2,
                                          att_b2, (float*)(ws + oSC));

  // 4. per-graph top-k and learned-graph CSR (symmetrized)
  topk_kernel<<<NGRAPH, 256, 0, stream>>>((const float*)(ws + oSC), src, dst, et,
                                          (int*)(ws + oKS), (int*)(ws + oKD), (int*)(ws + oKT));
  hipMemsetAsync(ws + oCNT, 0, (size_t)NNODES * 4, stream);
  csr_count<<<128, 256, 0, stream>>>((const int*)(ws + oKS), (const int*)(ws + oKD), (int*)(ws + oCNT));
  csr_offsets<<<NGRAPH, 128, 0, stream>>>((const int*)(ws + oCNT), (int*)(ws + oOFF), (int*)(ws + oCUR));
  csr_fill<<<128, 256, 0, stream>>>((const int*)(ws + oKS), (const int*)(ws + oKD),
                                    (const int*)(ws + oKT), (int*)(ws + oCUR),
                                    (int*)(ws + oNS), (int*)(ws + oNT));

  // 5. layer-0 transforms: one GEMM, Ntot=1280 (root + 4 relations), slabs of 256
  gemm_bt2<0, false, bf16_t><<<dim3(256, 5), 512, 0, stream>>>(
      h0, lw, nullptr, xw0, NNODES, 256, 8, 8388608L);

  // 6. layer-0 aggregation ONLY at the <=21 nodes/graph feeding the readout
  agg_struct_sel<<<320, 256, 0, stream>>>(xw0, et, conv_b, h1g);
  agg_csr_sel<<<1024, 256, 0, stream>>>(xw0, (const int*)(ws + oOFF), (const int*)(ws + oCNT),
                                        (const int*)(ws + oNS), (const int*)(ws + oNT),
                                        conv_b, h1g);

  // 7. layer-1 transforms on gathered rows (M=5376, Ntot=1280)
  gemm_bt2<0, false, bf16_t><<<dim3(42, 5), 512, 0, stream>>>(
      h1g, lw + 5 * 65536, nullptr, xw1, M1, 256, 8, (long)PLANE1);

  // 8. layer-1 aggregation at ptr nodes
  fagg_init<<<64, 256, 0, stream>>>(xw1, et, conv_b + 256, (float*)(ws + oH2I));
  fagg_learn<<<64, 256, 0, stream>>>(xw1, (const int*)(ws + oOFF), (const int*)(ws + oCNT),
                                     (const int*)(ws + oNT), conv_b + 256, (float*)(ws + oH2L));

  // 9. classifier + loss + y passthrough
  classifier_kernel<<<NGRAPH, 256, 0, stream>>>((const float*)(ws + oH2I), (const float*)(ws + oH2L),
                                                cls_w1, cls_b1, cls_w2, cls_b2, y,
                                                (float*)d_out, (float*)(ws + oLP));
  finalize_kernel<<<1, 256, 0, stream>>>((const float*)(ws + oLP), y, (float*)d_out);
}

// Round 12
// 441.897 us; speedup vs baseline: 1.1187x; 1.1187x over previous
//
#include <hip/hip_runtime.h>
#include <hip/hip_bf16.h>

typedef __bf16 bf16_t;
typedef __bf16 bf16x8 __attribute__((ext_vector_type(8)));
typedef __bf16 bf16x4 __attribute__((ext_vector_type(4)));
typedef float  f32x4  __attribute__((ext_vector_type(4)));

// Problem constants
#define NNODES 32768
#define NPER   128
#define NGRAPH 256
#define NEDGE  131072
#define EPERG  512
#define KKEEP  128
// gathered layer-1 row layout: [0,1280) initial branch (5 rows/graph),
// [1280, 1280+4096) learned branch (16-row stride/graph, root + <=8 srcs)
#define M1     5376
#define PLANE1 (M1 * 256)
// epilogue LDS tile stride (bf16): 264 = 16B-aligned rows + bank stagger
#define EPS    264

// ---------------------------------------------------------------- weight prep
__global__ void prep_kernel(const float* __restrict__ in_w,
                            const float* __restrict__ gen_w,
                            const float* __restrict__ att_w1,
                            const float* __restrict__ rel_w,
                            const float* __restrict__ root_w,
                            const float* __restrict__ in_b,
                            const float* __restrict__ gen_b,
                            bf16_t* __restrict__ wbf,    // [512][768]  (in_w ++ gen_w, B^T)
                            bf16_t* __restrict__ attT,   // [2048][256] (W1 src-half ++ dst-half)
                            bf16_t* __restrict__ lw,     // [2][1280][256] (root, rel r0..3)
                            float*  __restrict__ biasws) // [512] (in_b ++ gen_b)
{
  int idx = blockIdx.x * 256 + threadIdx.x;
  if (idx < 393216) {
    int which = idx / 196608, rem = idx % 196608;
    int n = rem / 768, k = rem % 768;
    const float* w = which ? gen_w : in_w;
    wbf[idx] = (bf16_t)w[k * 256 + n];
  } else if (idx < 917504) {
    int i2 = idx - 393216;
    int half = i2 / 262144, rem = i2 % 262144;
    int n = rem / 256, k = rem % 256;
    attT[i2] = (bf16_t)att_w1[(half * 256 + k) * 1024 + n];
  } else if (idx < 1572864) {
    int i3 = idx - 917504;
    int l = i3 / 327680, rem = i3 % 327680;
    int z = rem / 65536, r2 = rem % 65536;
    int n = r2 / 256, k = r2 % 256;
    float v = (z == 0) ? root_w[(l * 256 + k) * 256 + n]
                       : rel_w[((l * 4 + (z - 1)) * 256 + k) * 256 + n];
    lw[i3] = (bf16_t)v;
  } else if (idx < 1573376) {
    int j = idx - 1572864;
    biasws[j] = (j < 256) ? in_b[j] : gen_b[j - 256];
  }
}

// ---------------------------------------------------------------- bf16 MFMA GEMM (8-wave)
// C = act(A[M,K] @ BT[Ntot,K]^T + bias), BM=128, BN=256, BK=64, 8 waves (2x4).
// CAST_A: A is float*, reg-staged f32->bf16 with swizzled ds_write; else
// global_load_lds with inverse-swizzled source. LDS-transposed epilogue:
// fully-coalesced 16B stores. Slab-decomposed output (ncols=1<<colShift):
// C[slab*slabStride + row*ncols + (col&(ncols-1))]. Grid: (M/128, Ntot/256).
template<int ACT, bool HAS_BIAS, bool CAST_A>
__global__ __launch_bounds__(512, 4) void gemm_bt2(
    const void* __restrict__ Araw, const bf16_t* __restrict__ BT,
    const float* __restrict__ bias, bf16_t* __restrict__ C,
    int M, int K, int colShift, long slabStride)
{
  __shared__ bf16_t sA[8192];    // [128 rows][64 k] (16 KB)
  __shared__ bf16_t sB[16384];   // [256 rows][64 k] (32 KB); reused by epilogue
  const int tid = threadIdx.x;
  const int lane = tid & 63, wid = tid >> 6;
  const int wr = wid >> 2, wc = wid & 3;        // 2x4 wave grid
  const long row0 = (long)blockIdx.x * 128;
  const long n0  = (long)blockIdx.y * 256;

  f32x4 acc[4][4];
  #pragma unroll
  for (int m = 0; m < 4; ++m)
    #pragma unroll
    for (int n = 0; n < 4; ++n)
      #pragma unroll
      for (int j = 0; j < 4; ++j) acc[m][n][j] = 0.f;

  for (int kt = 0; kt < K; kt += 64) {
    // ---- stage A
    if constexpr (CAST_A) {
      const float* Af = (const float*)Araw;
      #pragma unroll
      for (int p = 0; p < 2; ++p) {
        const int idx = p * 4096 + tid * 8;      // element index in [128][64]
        const int row = idx >> 6;
        const int k8  = idx & 63;                // multiple of 8
        const float4* g = (const float4*)(Af + (row0 + row) * (long)K + kt + k8);
        float4 a = g[0], b = g[1];
        bf16x8 v;
        v[0]=(bf16_t)a.x; v[1]=(bf16_t)a.y; v[2]=(bf16_t)a.z; v[3]=(bf16_t)a.w;
        v[4]=(bf16_t)b.x; v[5]=(bf16_t)b.y; v[6]=(bf16_t)b.z; v[7]=(bf16_t)b.w;
        const int chunk = (k8 >> 3) ^ (row & 7); // swizzled LDS write (both-sides rule)
        *(bf16x8*)((char*)sA + row * 128 + chunk * 16) = v;
      }
    } else {
      const bf16_t* A = (const bf16_t*)Araw;
      #pragma unroll
      for (int p = 0; p < 2; ++p) {
        const int P = p * 8192 + tid * 16;           // LDS byte offset (linear)
        const int row = P >> 7;
        const int cch = ((P >> 4) & 7) ^ (row & 7);  // inverse-swizzled source chunk
        const bf16_t* ga = A + (row0 + row) * (long)K + kt + cch * 8;
        bf16_t* la = sA + p * 4096 + wid * 512;      // wave-uniform base; HW adds lane*16B
        __builtin_amdgcn_global_load_lds((__attribute__((address_space(1))) void*)ga,
                                         (__attribute__((address_space(3))) void*)la, 16, 0, 0);
      }
    }
    // ---- stage B
    #pragma unroll
    for (int q = 0; q < 4; ++q) {
      const int P = q * 8192 + tid * 16;
      const int row = P >> 7;                      // 0..255
      const int cch = ((P >> 4) & 7) ^ (row & 7);
      const bf16_t* gb = BT + (n0 + row) * (long)K + kt + cch * 8;
      bf16_t* lb = sB + q * 4096 + wid * 512;
      __builtin_amdgcn_global_load_lds((__attribute__((address_space(1))) void*)gb,
                                       (__attribute__((address_space(3))) void*)lb, 16, 0, 0);
    }
    __syncthreads();
    const char* cA = (const char*)sA;
    const char* cB = (const char*)sB;
    #pragma unroll
    for (int kk = 0; kk < 2; ++kk) {
      bf16x8 af[4], bfr[4];
      #pragma unroll
      for (int m = 0; m < 4; ++m) {
        const int row = wr * 64 + m * 16 + (lane & 15);
        const int inb = (((lane >> 4) * 16) + kk * 64) ^ ((row & 7) << 4);
        af[m] = *(const bf16x8*)(cA + (row & 127) * 128 + inb);
      }
      #pragma unroll
      for (int n = 0; n < 4; ++n) {
        const int row = wc * 64 + n * 16 + (lane & 15);
        const int inb = (((lane >> 4) * 16) + kk * 64) ^ ((row & 7) << 4);
        bfr[n] = *(const bf16x8*)(cB + row * 128 + inb);
      }
      #pragma unroll
      for (int m = 0; m < 4; ++m)
        #pragma unroll
        for (int n = 0; n < 4; ++n)
          acc[m][n] = __builtin_amdgcn_mfma_f32_16x16x32_bf16(af[m], bfr[n], acc[m][n], 0, 0, 0);
    }
    __syncthreads();
  }

  // ---- epilogue: LDS transpose -> fully-coalesced bf16x8 stores.
  // Per mg: block rows {mg*16..+16} U {64+mg*16..+16} x 256 cols = [32][256] tile.
  const int ncolsM1 = (1 << colShift) - 1;
  bf16_t* tb = sB;                               // 32 x EPS bf16 = 16.9 KB
  #pragma unroll
  for (int mg = 0; mg < 4; ++mg) {
    #pragma unroll
    for (int n = 0; n < 4; ++n) {
      const int col = wc * 64 + n * 16 + (lane & 15);
      float bv = 0.f;
      if (HAS_BIAS) bv = bias[(int)n0 + col];
      #pragma unroll
      for (int j = 0; j < 4; ++j) {
        const int lrow = wr * 16 + (lane >> 4) * 4 + j;
        float v = acc[mg][n][j] + bv;
        if (ACT == 1) v = (v > 0.f) ? v : 0.01f * v;
        tb[lrow * EPS + col] = (bf16_t)v;
      }
    }
    __syncthreads();
    #pragma unroll
    for (int p = 0; p < 2; ++p) {
      const int idx = p * 512 + tid;             // 0..1023
      const int lrow = idx >> 5;                 // 0..31
      const int c8 = (idx & 31) * 8;             // 0..248
      bf16x8 v = *(const bf16x8*)(tb + lrow * EPS + c8);
      const long row = row0 + (lrow >> 4) * 64 + mg * 16 + (lrow & 15);
      const int gcol = (int)n0 + c8;
      const int slab = gcol >> colShift;
      const int cin = gcol & ncolsM1;
      *(bf16x8*)(C + (long)slab * slabStride + (row << colShift) + cin) = v;
    }
    __syncthreads();
  }
}

// ---------------------------------------------------------------- edge scores
__global__ void score_kernel(const bf16_t* __restrict__ Abuf, const bf16_t* __restrict__ Bbuf,
                             const int* __restrict__ src, const int* __restrict__ dst,
                             const float* __restrict__ b1, const float* __restrict__ w2,
                             const float* __restrict__ b2, float* __restrict__ scores)
{
  __shared__ float sb1[1024], sw2[1024];
  for (int i = threadIdx.x; i < 1024; i += 256) { sb1[i] = b1[i]; sw2[i] = w2[i]; }
  __syncthreads();
  const int wid = threadIdx.x >> 6, lane = threadIdx.x & 63;
  const int e = blockIdx.x * 4 + wid;
  const int s = src[e], d = dst[e];
  const bf16x8* ar = (const bf16x8*)(Abuf + (long)s * 1024);
  const bf16x8* br = (const bf16x8*)(Bbuf + (long)d * 1024);
  float acc = 0.f;
  #pragma unroll
  for (int half = 0; half < 2; ++half) {
    bf16x8 av = ar[lane * 2 + half];
    bf16x8 bv = br[lane * 2 + half];
    const int jb = (lane * 2 + half) * 8;
    #pragma unroll
    for (int j = 0; j < 8; ++j) {
      float v = (float)av[j] + (float)bv[j] + sb1[jb + j];
      v = v > 0.f ? v : 0.f;
      acc += v * sw2[jb + j];
    }
  }
  #pragma unroll
  for (int off = 32; off > 0; off >>= 1) acc += __shfl_down(acc, off);
  if (lane == 0) scores[e] = acc + b2[0];
}

// ---------------------------------------------------------------- per-graph top-k
__global__ void topk_kernel(const float* __restrict__ scores,
                            const int* __restrict__ src, const int* __restrict__ dst,
                            const int* __restrict__ et,
                            int* __restrict__ ksrc, int* __restrict__ kdst, int* __restrict__ ktyp)
{
  const int g = blockIdx.x;
  __shared__ float sc[512];
  __shared__ int   id[512];
  for (int i = threadIdx.x; i < 512; i += 256) { sc[i] = scores[g * 512 + i]; id[i] = i; }
  for (int k2 = 2; k2 <= 512; k2 <<= 1) {
    for (int j = k2 >> 1; j > 0; j >>= 1) {
      __syncthreads();
      for (int t = threadIdx.x; t < 512; t += 256) {
        const int p = t ^ j;
        if (p > t) {
          float s1 = sc[t], s2 = sc[p];
          int   i1 = id[t], i2 = id[p];
          bool kgt = (s1 < s2) || (s1 == s2 && i1 > i2);
          bool up  = ((t & k2) == 0);
          if (kgt == up) { sc[t] = s2; sc[p] = s1; id[t] = i2; id[p] = i1; }
        }
      }
    }
  }
  __syncthreads();
  if (threadIdx.x < 128) {
    const int e = g * 512 + id[threadIdx.x];
    const int o = g * 128 + threadIdx.x;
    ksrc[o] = src[e]; kdst[o] = dst[e]; ktyp[o] = et[e];
  }
}

// ---------------------------------------------------------------- CSR build
__global__ void csr_count(const int* __restrict__ ksrc, const int* __restrict__ kdst,
                          int* __restrict__ counts)
{
  const int i = blockIdx.x * 256 + threadIdx.x;
  if (i >= NGRAPH * KKEEP) return;
  atomicAdd(&counts[kdst[i]], 1);
  atomicAdd(&counts[ksrc[i]], 1);
}

__global__ void csr_offsets(const int* __restrict__ counts, int* __restrict__ offs,
                            int* __restrict__ cursor)
{
  const int g = blockIdx.x, t = threadIdx.x;   // 128 threads
  __shared__ int s[128];
  const int mc = counts[g * 128 + t];
  s[t] = mc;
  __syncthreads();
  for (int dd = 1; dd < 128; dd <<= 1) {
    int v = (t >= dd) ? s[t - dd] : 0;
    __syncthreads();
    s[t] += v;
    __syncthreads();
  }
  const int o = g * 256 + (s[t] - mc);
  offs[g * 128 + t] = o;
  cursor[g * 128 + t] = o;
}

__global__ void csr_fill(const int* __restrict__ ksrc, const int* __restrict__ kdst,
                         const int* __restrict__ ktyp, int* __restrict__ cursor,
                         int* __restrict__ nsrc, int* __restrict__ ntyp)
{
  const int i = blockIdx.x * 256 + threadIdx.x;
  if (i >= NGRAPH * KKEEP) return;
  const int s = ksrc[i], d = kdst[i], t = ktyp[i];
  int p = atomicAdd(&cursor[d], 1); nsrc[p] = s; ntyp[p] = t;
  int q = atomicAdd(&cursor[s], 1); nsrc[q] = d; ntyp[q] = t;
}

// ---------------------------------------------------------------- selected layer-0 agg
// xw0 layout: [5][NNODES][256] bf16 (z=0 root, z=1+r relation transforms).

// Initial branch (ring graph): rows g*5 + {0:node0, o:node 128-o (o=1..4)}.
__global__ void agg_struct_sel(const bf16_t* __restrict__ xw0, const int* __restrict__ et,
                               const float* __restrict__ conv_b, bf16_t* __restrict__ h1g)
{
  const int wid = threadIdx.x >> 6, lane = threadIdx.x & 63;
  const int row = blockIdx.x * 4 + wid;         // 0..1279
  const int g = row / 5, slot = row % 5;
  const int d = (slot == 0) ? 0 : (128 - slot);
  const int n = g * 128 + d;
  const int c = lane * 4;
  int rt[4], si[4];
  #pragma unroll
  for (int oo = 0; oo < 4; ++oo) {
    const int i = (d - oo - 1 + 128) & 127;
    rt[oo] = et[g * 512 + oo * 128 + i];
    si[oo] = g * 128 + i;
  }
  const float4 cb = *(const float4*)(conv_b + c);
  bf16x4 rv = *(const bf16x4*)(xw0 + (long)n * 256 + c);
  float acc[4] = { (float)rv[0] + cb.x, (float)rv[1] + cb.y,
                   (float)rv[2] + cb.z, (float)rv[3] + cb.w };
  float s0[4] = {0,0,0,0}, s1[4] = {0,0,0,0}, s2[4] = {0,0,0,0}, s3[4] = {0,0,0,0};
  int d0 = 0, d1 = 0, d2 = 0, d3 = 0;
  #pragma unroll
  for (int oo = 0; oo < 4; ++oo) {
    const int t = rt[oo];
    bf16x4 w = *(const bf16x4*)(xw0 + ((long)(t + 1) * NNODES + si[oo]) * 256 + c);
    if (t == 0)      { d0++; for (int j = 0; j < 4; ++j) s0[j] += (float)w[j]; }
    else if (t == 1) { d1++; for (int j = 0; j < 4; ++j) s1[j] += (float)w[j]; }
    else if (t == 2) { d2++; for (int j = 0; j < 4; ++j) s2[j] += (float)w[j]; }
    else             { d3++; for (int j = 0; j < 4; ++j) s3[j] += (float)w[j]; }
  }
  if (d0) { float r = 1.f / d0; for (int j = 0; j < 4; ++j) acc[j] += s0[j] * r; }
  if (d1) { float r = 1.f / d1; for (int j = 0; j < 4; ++j) acc[j] += s1[j] * r; }
  if (d2) { float r = 1.f / d2; for (int j = 0; j < 4; ++j) acc[j] += s2[j] * r; }
  if (d3) { float r = 1.f / d3; for (int j = 0; j < 4; ++j) acc[j] += s3[j] * r; }
  bf16x4 ov; for (int j = 0; j < 4; ++j) ov[j] = (bf16_t)acc[j];
  *(bf16x4*)(h1g + (long)row * 256 + c) = ov;
}

// Learned branch (CSR graph): rows 1280 + g*16 + {0:ptr, 1+j: nsrc[off0+j]}.
__global__ void agg_csr_sel(const bf16_t* __restrict__ xw0, const int* __restrict__ offs,
                            const int* __restrict__ cnts, const int* __restrict__ nsrc,
                            const int* __restrict__ ntyp, const float* __restrict__ conv_b,
                            bf16_t* __restrict__ h1g)
{
  const int wid = threadIdx.x >> 6, lane = threadIdx.x & 63;
  const int idx = blockIdx.x * 4 + wid;         // 0..4095
  const int g = idx >> 4, slot = idx & 15;
  const int off0 = offs[g * 128], cnt0 = cnts[g * 128];
  if (slot > cnt0) return;                      // slot 0 = root, 1..cnt0 = srcs
  const int v = (slot == 0) ? g * 128 : nsrc[off0 + slot - 1];
  const int row = 1280 + idx;
  const int offv = offs[v], cntv = cnts[v];
  const int c = lane * 4;
  const float4 cb = *(const float4*)(conv_b + c);
  bf16x4 rv = *(const bf16x4*)(xw0 + (long)v * 256 + c);
  float acc[4] = { (float)rv[0] + cb.x, (float)rv[1] + cb.y,
                   (float)rv[2] + cb.z, (float)rv[3] + cb.w };
  float s0[4] = {0,0,0,0}, s1[4] = {0,0,0,0}, s2[4] = {0,0,0,0}, s3[4] = {0,0,0,0};
  int d0 = 0, d1 = 0, d2 = 0, d3 = 0;
  for (int j = 0; j < cntv; ++j) {
    const int t = ntyp[offv + j];
    const int sv = nsrc[offv + j];
    bf16x4 w = *(const bf16x4*)(xw0 + ((long)(t + 1) * NNODES + sv) * 256 + c);
    if (t == 0)      { d0++; for (int q = 0; q < 4; ++q) s0[q] += (float)w[q]; }
    else if (t == 1) { d1++; for (int q = 0; q < 4; ++q) s1[q] += (float)w[q]; }
    else if (t == 2) { d2++; for (int q = 0; q < 4; ++q) s2[q] += (float)w[q]; }
    else             { d3++; for (int q = 0; q < 4; ++q) s3[q] += (float)w[q]; }
  }
  if (d0) { float r = 1.f / d0; for (int q = 0; q < 4; ++q) acc[q] += s0[q] * r; }
  if (d1) { float r = 1.f / d1; for (int q = 0; q < 4; ++q) acc[q] += s1[q] * r; }
  if (d2) { float r = 1.f / d2; for (int q = 0; q < 4; ++q) acc[q] += s2[q] * r; }
  if (d3) { float r = 1.f / d3; for (int q = 0; q < 4; ++q) acc[q] += s3[q] * r; }
  bf16x4 ov; for (int q = 0; q < 4; ++q) ov[q] = (bf16_t)acc[q];
  *(bf16x4*)(h1g + (long)row * 256 + c) = ov;
}

// ---------------------------------------------------------------- final (layer-1) agg at ptr
// xw1 layout: [5][M1][256] bf16 over the gathered rows.
__global__ void fagg_init(const bf16_t* __restrict__ xw1, const int* __restrict__ et,
                          const float* __restrict__ conv_b1, float* __restrict__ h2I)
{
  const int wid = threadIdx.x >> 6, lane = threadIdx.x & 63;
  const int g = blockIdx.x * 4 + wid;           // 0..255
  const int base = g * 5;
  const int c = lane * 4;
  const float4 cb = *(const float4*)(conv_b1 + c);
  bf16x4 rv = *(const bf16x4*)(xw1 + (long)base * 256 + c);
  float acc[4] = { (float)rv[0] + cb.x, (float)rv[1] + cb.y,
                   (float)rv[2] + cb.z, (float)rv[3] + cb.w };
  float s0[4] = {0,0,0,0}, s1[4] = {0,0,0,0}, s2[4] = {0,0,0,0}, s3[4] = {0,0,0,0};
  int d0 = 0, d1 = 0, d2 = 0, d3 = 0;
  #pragma unroll
  for (int o = 1; o <= 4; ++o) {
    const int t = et[g * 512 + (o - 1) * 128 + (128 - o)];
    bf16x4 w = *(const bf16x4*)(xw1 + ((long)(t + 1) * M1 + base + o) * 256 + c);
    if (t == 0)      { d0++; for (int q = 0; q < 4; ++q) s0[q] += (float)w[q]; }
    else if (t == 1) { d1++; for (int q = 0; q < 4; ++q) s1[q] += (float)w[q]; }
    else if (t == 2) { d2++; for (int q = 0; q < 4; ++q) s2[q] += (float)w[q]; }
    else             { d3++; for (int q = 0; q < 4; ++q) s3[q] += (float)w[q]; }
  }
  if (d0) { float r = 1.f / d0; for (int q = 0; q < 4; ++q) acc[q] += s0[q] * r; }
  if (d1) { float r = 1.f / d1; for (int q = 0; q < 4; ++q) acc[q] += s1[q] * r; }
  if (d2) { float r = 1.f / d2; for (int q = 0; q < 4; ++q) acc[q] += s2[q] * r; }
  if (d3) { float r = 1.f / d3; for (int q = 0; q < 4; ++q) acc[q] += s3[q] * r; }
  *(float4*)(h2I + (long)g * 256 + c) = make_float4(acc[0], acc[1], acc[2], acc[3]);
}

__global__ void fagg_learn(const bf16_t* __restrict__ xw1, const int* __restrict__ offs,
                           const int* __restrict__ cnts, const int* __restrict__ ntyp,
                           const float* __restrict__ conv_b1, float* __restrict__ h2L)
{
  const int wid = threadIdx.x >> 6, lane = threadIdx.x & 63;
  const int g = blockIdx.x * 4 + wid;           // 0..255
  const int base = 1280 + g * 16;
  const int off0 = offs[g * 128], cnt0 = cnts[g * 128];
  const int c = lane * 4;
  const float4 cb = *(const float4*)(conv_b1 + c);
  bf16x4 rv = *(const bf16x4*)(xw1 + (long)base * 256 + c);
  float acc[4] = { (float)rv[0] + cb.x, (float)rv[1] + cb.y,
                   (float)rv[2] + cb.z, (float)rv[3] + cb.w };
  float s0[4] = {0,0,0,0}, s1[4] = {0,0,0,0}, s2[4] = {0,0,0,0}, s3[4] = {0,0,0,0};
  int d0 = 0, d1 = 0, d2 = 0, d3 = 0;
  for (int j = 0; j < cnt0; ++j) {
    const int t = ntyp[off0 + j];
    bf16x4 w = *(const bf16x4*)(xw1 + ((long)(t + 1) * M1 + base + 1 + j) * 256 + c);
    if (t == 0)      { d0++; for (int q = 0; q < 4; ++q) s0[q] += (float)w[q]; }
    else if (t == 1) { d1++; for (int q = 0; q < 4; ++q) s1[q] += (float)w[q]; }
    else if (t == 2) { d2++; for (int q = 0; q < 4; ++q) s2[q] += (float)w[q]; }
    else             { d3++; for (int q = 0; q < 4; ++q) s3[q] += (float)w[q]; }
  }
  if (d0) { float r = 1.f / d0; for (int q = 0; q < 4; ++q) acc[q] += s0[q] * r; }
  if (d1) { float r = 1.f / d1; for (int q = 0; q < 4; ++q) acc[q] += s1[q] * r; }
  if (d2) { float r = 1.f / d2; for (int q = 0; q < 4; ++q) acc[q] += s2[q] * r; }
  if (d3) { float r = 1.f / d3; for (int q = 0; q < 4; ++q) acc[q] += s3[q] * r; }
  *(float4*)(h2L + (long)g * 256 + c) = make_float4(acc[0], acc[1], acc[2], acc[3]);
}

// ---------------------------------------------------------------- classifier head
__global__ void classifier_kernel(const float* __restrict__ h2I, const float* __restrict__ h2L,
                                  const float* __restrict__ w1, const float* __restrict__ b1,
                                  const float* __restrict__ w2, const float* __restrict__ b2,
                                  const int* __restrict__ y, float* __restrict__ out,
                                  float* __restrict__ logp)
{
  const int g = blockIdx.x, t = threadIdx.x;
  __shared__ float rep[512];
  __shared__ float hid[256];
  __shared__ float lg[4];
  rep[t] = h2I[g * 256 + t];
  rep[256 + t] = h2L[g * 256 + t];
  __syncthreads();
  float a = b1[t];
  for (int i = 0; i < 512; ++i) a += rep[i] * w1[i * 256 + t];
  hid[t] = a > 0.f ? a : 0.01f * a;
  __syncthreads();
  if (t < 4) {
    float s = b2[t];
    for (int j = 0; j < 256; ++j) s += hid[j] * w2[j * 4 + t];
    lg[t] = s;
    out[g * 4 + t] = s;
  }
  __syncthreads();
  if (t == 0) {
    float m = fmaxf(fmaxf(lg[0], lg[1]), fmaxf(lg[2], lg[3]));
    float se = expf(lg[0] - m) + expf(lg[1] - m) + expf(lg[2] - m) + expf(lg[3] - m);
    logp[g] = lg[y[g]] - (m + logf(se));
  }
}

__global__ void finalize_kernel(const float* __restrict__ logp, const int* __restrict__ y,
                                float* __restrict__ out)
{
  __shared__ float s[256];
  const int t = threadIdx.x;
  s[t] = logp[t];
  __syncthreads();
  for (int d = 128; d > 0; d >>= 1) {
    if (t < d) s[t] += s[t + d];
    __syncthreads();
  }
  if (t == 0) out[1024] = -s[0] / 256.f;
  out[1025 + t] = (float)y[t];
}

// ---------------------------------------------------------------- launcher
extern "C" void kernel_launch(void* const* d_in, const int* in_sizes, int n_in,
                              void* d_out, int out_size, void* d_ws, size_t ws_size,
                              hipStream_t stream)
{
  (void)in_sizes; (void)n_in; (void)out_size; (void)ws_size;
  const float* x      = (const float*)d_in[0];
  const int*   ei     = (const int*)d_in[1];
  const int*   et     = (const int*)d_in[2];
  const int*   y      = (const int*)d_in[3];
  const float* gen_w  = (const float*)d_in[4];
  const float* gen_b  = (const float*)d_in[5];
  const float* att_w1 = (const float*)d_in[6];
  const float* att_b1 = (const float*)d_in[7];
  const float* att_w2 = (const float*)d_in[8];
  const float* att_b2 = (const float*)d_in[9];
  const float* in_w   = (const float*)d_in[10];
  const float* in_b   = (const float*)d_in[11];
  const float* rel_w  = (const float*)d_in[12];
  const float* root_w = (const float*)d_in[13];
  const float* conv_b = (const float*)d_in[14];
  const float* cls_w1 = (const float*)d_in[15];
  const float* cls_b1 = (const float*)d_in[16];
  const float* cls_w2 = (const float*)d_in[17];
  const float* cls_b2 = (const float*)d_in[18];
  const int* src = ei;
  const int* dst = ei + NEDGE;

  char* ws = (char*)d_ws;
  // Region 0 (time-shared, sequential lifetimes):
  //   AB (134.2MB) -> xw0 (83.9MB); region0 = 134.2MB. x consumed directly (fused cast).
  size_t off = 134217728;
  const size_t oBIG = 0;
  auto alloc = [&](size_t bytes) { size_t r = off; off += (bytes + 255) & ~(size_t)255; return r; };
  const size_t oH0  = alloc((size_t)NNODES * 256 * 2);
  const size_t oHG  = alloc((size_t)NNODES * 256 * 2);   // adjacent to oH0 (N-batched GEMM)
  const size_t oH1G = alloc((size_t)M1 * 256 * 2);
  const size_t oXW1 = alloc((size_t)5 * M1 * 256 * 2);
  const size_t oSC  = alloc((size_t)NEDGE * 4);
  const size_t oKS  = alloc((size_t)NGRAPH * KKEEP * 4);
  const size_t oKD  = alloc((size_t)NGRAPH * KKEEP * 4);
  const size_t oKT  = alloc((size_t)NGRAPH * KKEEP * 4);
  const size_t oCNT = alloc((size_t)NNODES * 4);
  const size_t oOFF = alloc((size_t)NNODES * 4);
  const size_t oCUR = alloc((size_t)NNODES * 4);
  const size_t oNS  = alloc((size_t)2 * NGRAPH * KKEEP * 4);
  const size_t oNT  = alloc((size_t)2 * NGRAPH * KKEEP * 4);
  const size_t oWBF = alloc((size_t)2 * 256 * 768 * 2);
  const size_t oATT = alloc((size_t)2 * 1024 * 256 * 2);
  const size_t oLW  = alloc((size_t)2 * 5 * 256 * 256 * 2);
  const size_t oBIA = alloc(512 * 4);
  const size_t oH2I = alloc((size_t)NGRAPH * 256 * 4);
  const size_t oH2L = alloc((size_t)NGRAPH * 256 * 4);
  const size_t oLP  = alloc((size_t)NGRAPH * 4);

  bf16_t* AB   = (bf16_t*)(ws + oBIG);   // [2][32768][1024]
  bf16_t* xw0  = (bf16_t*)(ws + oBIG);   // [5][NNODES][256]
  bf16_t* h0   = (bf16_t*)(ws + oH0);
  bf16_t* hg   = (bf16_t*)(ws + oHG);
  bf16_t* h1g  = (bf16_t*)(ws + oH1G);   // [M1][256] gathered layer-1 input
  bf16_t* xw1  = (bf16_t*)(ws + oXW1);   // [5][M1][256]
  bf16_t* wbf  = (bf16_t*)(ws + oWBF);
  bf16_t* attT = (bf16_t*)(ws + oATT);
  bf16_t* lw   = (bf16_t*)(ws + oLW);
  float*  bias = (float*)(ws + oBIA);

  // 1. weight prep
  prep_kernel<<<6146, 256, 0, stream>>>(in_w, gen_w, att_w1, rel_w, root_w, in_b, gen_b,
                                        wbf, attT, lw, bias);

  // 2. h0 = leaky(x@in_w+b), hg = leaky(x@gen_w+b): fused f32 cast, Ntot=512, slabs of 256
  gemm_bt2<1, true, true><<<dim3(256, 2), 512, 0, stream>>>(
      (const void*)x, wbf, bias, h0, NNODES, 768, 8, 8388608L);

  // 3. A/B node factors: Ntot=2048, slabs of 1024; then per-edge scores
  gemm_bt2<0, false, false><<<dim3(256, 8), 512, 0, stream>>>(
      (const void*)hg, attT, nullptr, AB, NNODES, 256, 10, 33554432L);
  score_kernel<<<32768, 256, 0, stream>>>(AB, AB + 33554432L, src, dst, att_b1, att_w2,
                                          att_b2, (float*)(ws + oSC));

  // 4. per-graph top-k and learned-graph CSR (symmetrized)
  topk_kernel<<<NGRAPH, 256, 0, stream>>>((const float*)(ws + oSC), src, dst, et,
                                          (int*)(ws + oKS), (int*)(ws + oKD), (int*)(ws + oKT));
  hipMemsetAsync(ws + oCNT, 0, (size_t)NNODES * 4, stream);
  csr_count<<<128, 256, 0, stream>>>((const int*)(ws + oKS), (const int*)(ws + oKD), (int*)(ws + oCNT));
  csr_offsets<<<NGRAPH, 128, 0, stream>>>((const int*)(ws + oCNT), (int*)(ws + oOFF), (int*)(ws + oCUR));
  csr_fill<<<128, 256, 0, stream>>>((const int*)(ws + oKS), (const int*)(ws + oKD),
                                    (const int*)(ws + oKT), (int*)(ws + oCUR),
                                    (int*)(ws + oNS), (int*)(ws + oNT));

  // 5. layer-0 transforms: Ntot=1280 (root + 4 relations), slabs of 256
  gemm_bt2<0, false, false><<<dim3(256, 5), 512, 0, stream>>>(
      (const void*)h0, lw, nullptr, xw0, NNODES, 256, 8, 8388608L);

  // 6. layer-0 aggregation ONLY at the <=21 nodes/graph feeding the readout
  agg_struct_sel<<<320, 256, 0, stream>>>(xw0, et, conv_b, h1g);
  agg_csr_sel<<<1024, 256, 0, stream>>>(xw0, (const int*)(ws + oOFF), (const int*)(ws + oCNT),
                                        (const int*)(ws + oNS), (const int*)(ws + oNT),
                                        conv_b, h1g);

  // 7. layer-1 transforms on gathered rows (M=5376, Ntot=1280)
  gemm_bt2<0, false, false><<<dim3(42, 5), 512, 0, stream>>>(
      (const void*)h1g, lw + 5 * 65536, nullptr, xw1, M1, 256, 8, (long)PLANE1);

  // 8. layer-1 aggregation at ptr nodes
  fagg_init<<<64, 256, 0, stream>>>(xw1, et, conv_b + 256, (float*)(ws + oH2I));
  fagg_learn<<<64, 256, 0, stream>>>(xw1, (const int*)(ws + oOFF), (const int*)(ws + oCNT),
                                     (const int*)(ws + oNT), conv_b + 256, (float*)(ws + oH2L));

  // 9. classifier + loss + y passthrough
  classifier_kernel<<<NGRAPH, 256, 0, stream>>>((const float*)(ws + oH2I), (const float*)(ws + oH2L),
                                                cls_w1, cls_b1, cls_w2, cls_b2, y,
                                                (float*)d_out, (float*)(ws + oLP));
  finalize_kernel<<<1, 256, 0, stream>>>((const float*)(ws + oLP), y, (float*)d_out);
}

// Round 13
// 419.804 us; speedup vs baseline: 1.1776x; 1.0526x over previous
//
#include <hip/hip_runtime.h>
#include <hip/hip_bf16.h>

typedef __bf16 bf16_t;
typedef __bf16 bf16x8 __attribute__((ext_vector_type(8)));
typedef __bf16 bf16x4 __attribute__((ext_vector_type(4)));
typedef float  f32x4  __attribute__((ext_vector_type(4)));

// Problem constants
#define NNODES 32768
#define NPER   128
#define NGRAPH 256
#define NEDGE  131072
#define EPERG  512
#define KKEEP  128
// gathered layer-1 row layout: [0,1280) initial branch (5 rows/graph),
// [1280, 1280+4096) learned branch (16-row stride/graph, root + <=8 srcs)
#define M1     5376
#define PLANE1 (M1 * 256)
// epilogue LDS tile stride (bf16): 264 = 16B-aligned rows + bank stagger
#define EPS    264

// ---------------------------------------------------------------- weight prep
__global__ void prep_kernel(const float* __restrict__ in_w,
                            const float* __restrict__ gen_w,
                            const float* __restrict__ att_w1,
                            const float* __restrict__ rel_w,
                            const float* __restrict__ root_w,
                            const float* __restrict__ in_b,
                            const float* __restrict__ gen_b,
                            bf16_t* __restrict__ wbf,    // [512][768]  (in_w ++ gen_w, B^T)
                            bf16_t* __restrict__ attT,   // [2048][256] (W1 src-half ++ dst-half)
                            bf16_t* __restrict__ lw,     // [2][1280][256] (root, rel r0..3)
                            float*  __restrict__ biasws) // [512] (in_b ++ gen_b)
{
  int idx = blockIdx.x * 256 + threadIdx.x;
  if (idx < 393216) {
    int which = idx / 196608, rem = idx % 196608;
    int n = rem / 768, k = rem % 768;
    const float* w = which ? gen_w : in_w;
    wbf[idx] = (bf16_t)w[k * 256 + n];
  } else if (idx < 917504) {
    int i2 = idx - 393216;
    int half = i2 / 262144, rem = i2 % 262144;
    int n = rem / 256, k = rem % 256;
    attT[i2] = (bf16_t)att_w1[(half * 256 + k) * 1024 + n];
  } else if (idx < 1572864) {
    int i3 = idx - 917504;
    int l = i3 / 327680, rem = i3 % 327680;
    int z = rem / 65536, r2 = rem % 65536;
    int n = r2 / 256, k = r2 % 256;
    float v = (z == 0) ? root_w[(l * 256 + k) * 256 + n]
                       : rel_w[((l * 4 + (z - 1)) * 256 + k) * 256 + n];
    lw[i3] = (bf16_t)v;
  } else if (idx < 1573376) {
    int j = idx - 1572864;
    biasws[j] = (j < 256) ? in_b[j] : gen_b[j - 256];
  }
}

// ---------------------------------------------------------------- bf16 MFMA GEMM (8-wave)
// C = act(A[M,K] @ BT[Ntot,K]^T + bias), BM=128, BN=256, BK=64, 8 waves (2x4).
// CAST_A: A is float*, reg-staged f32->bf16 with swizzled ds_write; else
// global_load_lds with inverse-swizzled source. LDS-transposed epilogue:
// fully-coalesced 16B stores. Slab-decomposed output (ncols=1<<colShift):
// C[slab*slabStride + row*ncols + (col&(ncols-1))]. Grid: (M/128, Ntot/256).
template<int ACT, bool HAS_BIAS, bool CAST_A>
__global__ __launch_bounds__(512, 4) void gemm_bt2(
    const void* __restrict__ Araw, const bf16_t* __restrict__ BT,
    const float* __restrict__ bias, bf16_t* __restrict__ C,
    int M, int K, int colShift, long slabStride)
{
  __shared__ bf16_t sA[8192];    // [128 rows][64 k] (16 KB)
  __shared__ bf16_t sB[16384];   // [256 rows][64 k] (32 KB); reused by epilogue
  const int tid = threadIdx.x;
  const int lane = tid & 63, wid = tid >> 6;
  const int wr = wid >> 2, wc = wid & 3;        // 2x4 wave grid
  const long row0 = (long)blockIdx.x * 128;
  const long n0  = (long)blockIdx.y * 256;

  f32x4 acc[4][4];
  #pragma unroll
  for (int m = 0; m < 4; ++m)
    #pragma unroll
    for (int n = 0; n < 4; ++n)
      #pragma unroll
      for (int j = 0; j < 4; ++j) acc[m][n][j] = 0.f;

  for (int kt = 0; kt < K; kt += 64) {
    // ---- stage A
    if constexpr (CAST_A) {
      const float* Af = (const float*)Araw;
      #pragma unroll
      for (int p = 0; p < 2; ++p) {
        const int idx = p * 4096 + tid * 8;      // element index in [128][64]
        const int row = idx >> 6;
        const int k8  = idx & 63;                // multiple of 8
        const float4* g = (const float4*)(Af + (row0 + row) * (long)K + kt + k8);
        float4 a = g[0], b = g[1];
        bf16x8 v;
        v[0]=(bf16_t)a.x; v[1]=(bf16_t)a.y; v[2]=(bf16_t)a.z; v[3]=(bf16_t)a.w;
        v[4]=(bf16_t)b.x; v[5]=(bf16_t)b.y; v[6]=(bf16_t)b.z; v[7]=(bf16_t)b.w;
        const int chunk = (k8 >> 3) ^ (row & 7); // swizzled LDS write (both-sides rule)
        *(bf16x8*)((char*)sA + row * 128 + chunk * 16) = v;
      }
    } else {
      const bf16_t* A = (const bf16_t*)Araw;
      #pragma unroll
      for (int p = 0; p < 2; ++p) {
        const int P = p * 8192 + tid * 16;           // LDS byte offset (linear)
        const int row = P >> 7;
        const int cch = ((P >> 4) & 7) ^ (row & 7);  // inverse-swizzled source chunk
        const bf16_t* ga = A + (row0 + row) * (long)K + kt + cch * 8;
        bf16_t* la = sA + p * 4096 + wid * 512;      // wave-uniform base; HW adds lane*16B
        __builtin_amdgcn_global_load_lds((__attribute__((address_space(1))) void*)ga,
                                         (__attribute__((address_space(3))) void*)la, 16, 0, 0);
      }
    }
    // ---- stage B
    #pragma unroll
    for (int q = 0; q < 4; ++q) {
      const int P = q * 8192 + tid * 16;
      const int row = P >> 7;                      // 0..255
      const int cch = ((P >> 4) & 7) ^ (row & 7);
      const bf16_t* gb = BT + (n0 + row) * (long)K + kt + cch * 8;
      bf16_t* lb = sB + q * 4096 + wid * 512;
      __builtin_amdgcn_global_load_lds((__attribute__((address_space(1))) void*)gb,
                                       (__attribute__((address_space(3))) void*)lb, 16, 0, 0);
    }
    __syncthreads();
    const char* cA = (const char*)sA;
    const char* cB = (const char*)sB;
    #pragma unroll
    for (int kk = 0; kk < 2; ++kk) {
      bf16x8 af[4], bfr[4];
      #pragma unroll
      for (int m = 0; m < 4; ++m) {
        const int row = wr * 64 + m * 16 + (lane & 15);
        const int inb = (((lane >> 4) * 16) + kk * 64) ^ ((row & 7) << 4);
        af[m] = *(const bf16x8*)(cA + (row & 127) * 128 + inb);
      }
      #pragma unroll
      for (int n = 0; n < 4; ++n) {
        const int row = wc * 64 + n * 16 + (lane & 15);
        const int inb = (((lane >> 4) * 16) + kk * 64) ^ ((row & 7) << 4);
        bfr[n] = *(const bf16x8*)(cB + row * 128 + inb);
      }
      #pragma unroll
      for (int m = 0; m < 4; ++m)
        #pragma unroll
        for (int n = 0; n < 4; ++n)
          acc[m][n] = __builtin_amdgcn_mfma_f32_16x16x32_bf16(af[m], bfr[n], acc[m][n], 0, 0, 0);
    }
    __syncthreads();
  }

  // ---- epilogue: LDS transpose -> fully-coalesced bf16x8 stores.
  // Per mg: block rows {mg*16..+16} U {64+mg*16..+16} x 256 cols = [32][256] tile.
  const int ncolsM1 = (1 << colShift) - 1;
  bf16_t* tb = sB;                               // 32 x EPS bf16 = 16.9 KB
  #pragma unroll
  for (int mg = 0; mg < 4; ++mg) {
    #pragma unroll
    for (int n = 0; n < 4; ++n) {
      const int col = wc * 64 + n * 16 + (lane & 15);
      float bv = 0.f;
      if (HAS_BIAS) bv = bias[(int)n0 + col];
      #pragma unroll
      for (int j = 0; j < 4; ++j) {
        const int lrow = wr * 16 + (lane >> 4) * 4 + j;
        float v = acc[mg][n][j] + bv;
        if (ACT == 1) v = (v > 0.f) ? v : 0.01f * v;
        tb[lrow * EPS + col] = (bf16_t)v;
      }
    }
    __syncthreads();
    #pragma unroll
    for (int p = 0; p < 2; ++p) {
      const int idx = p * 512 + tid;             // 0..1023
      const int lrow = idx >> 5;                 // 0..31
      const int c8 = (idx & 31) * 8;             // 0..248
      bf16x8 v = *(const bf16x8*)(tb + lrow * EPS + c8);
      const long row = row0 + (lrow >> 4) * 64 + mg * 16 + (lrow & 15);
      const int gcol = (int)n0 + c8;
      const int slab = gcol >> colShift;
      const int cin = gcol & ncolsM1;
      *(bf16x8*)(C + (long)slab * slabStride + (row << colShift) + cin) = v;
    }
    __syncthreads();
  }
}

// ---------------------------------------------------------------- edge scores
// Structured edges: edge e = g*512 + o*128 + i has src=g*128+i,
// dst=g*128+(i+o+1)%128. One wave per (g,i): A row read once, 4 B rows,
// b1/w2 in registers (per-lane dims [lane*16, lane*16+16) — same mapping
// and accumulation order as before => bit-identical scores).
__global__ __launch_bounds__(256) void score_kernel(
    const bf16_t* __restrict__ Abuf, const bf16_t* __restrict__ Bbuf,
    const float* __restrict__ b1, const float* __restrict__ w2,
    const float* __restrict__ b2, float* __restrict__ scores)
{
  const int wid = threadIdx.x >> 6, lane = threadIdx.x & 63;
  const int w = blockIdx.x * 4 + wid;           // 0..32767
  const int g = w >> 7, i = w & 127;
  const int jb = lane * 16;
  // per-lane constants in registers
  float rb1[16], rw2[16];
  #pragma unroll
  for (int q = 0; q < 4; ++q) {
    *(float4*)(rb1 + q * 4) = *(const float4*)(b1 + jb + q * 4);
    *(float4*)(rw2 + q * 4) = *(const float4*)(w2 + jb + q * 4);
  }
  // A row (16 dims/lane, two bf16x8 halves)
  const bf16x8* ar = (const bf16x8*)(Abuf + (long)(g * 128 + i) * 1024);
  bf16x8 a0 = ar[lane * 2], a1 = ar[lane * 2 + 1];
  float af[16];
  #pragma unroll
  for (int j = 0; j < 8; ++j) { af[j] = (float)a0[j]; af[8 + j] = (float)a1[j]; }
  const float b2v = b2[0];

  #pragma unroll
  for (int o = 0; o < 4; ++o) {
    const int d = (i + o + 1) & 127;
    const bf16x8* br = (const bf16x8*)(Bbuf + (long)(g * 128 + d) * 1024);
    bf16x8 b0 = br[lane * 2], b1v_ = br[lane * 2 + 1];
    float acc = 0.f;
    #pragma unroll
    for (int j = 0; j < 8; ++j) {
      float v = af[j] + (float)b0[j] + rb1[j];
      v = v > 0.f ? v : 0.f;
      acc += v * rw2[j];
    }
    #pragma unroll
    for (int j = 0; j < 8; ++j) {
      float v = af[8 + j] + (float)b1v_[j] + rb1[8 + j];
      v = v > 0.f ? v : 0.f;
      acc += v * rw2[8 + j];
    }
    #pragma unroll
    for (int off = 32; off > 0; off >>= 1) acc += __shfl_down(acc, off);
    if (lane == 0) scores[g * 512 + o * 128 + i] = acc + b2v;
  }
}

// ---------------------------------------------------------------- per-graph top-k
__global__ void topk_kernel(const float* __restrict__ scores,
                            const int* __restrict__ src, const int* __restrict__ dst,
                            const int* __restrict__ et,
                            int* __restrict__ ksrc, int* __restrict__ kdst, int* __restrict__ ktyp)
{
  const int g = blockIdx.x;
  __shared__ float sc[512];
  __shared__ int   id[512];
  for (int i = threadIdx.x; i < 512; i += 256) { sc[i] = scores[g * 512 + i]; id[i] = i; }
  for (int k2 = 2; k2 <= 512; k2 <<= 1) {
    for (int j = k2 >> 1; j > 0; j >>= 1) {
      __syncthreads();
      for (int t = threadIdx.x; t < 512; t += 256) {
        const int p = t ^ j;
        if (p > t) {
          float s1 = sc[t], s2 = sc[p];
          int   i1 = id[t], i2 = id[p];
          bool kgt = (s1 < s2) || (s1 == s2 && i1 > i2);
          bool up  = ((t & k2) == 0);
          if (kgt == up) { sc[t] = s2; sc[p] = s1; id[t] = i2; id[p] = i1; }
        }
      }
    }
  }
  __syncthreads();
  if (threadIdx.x < 128) {
    const int e = g * 512 + id[threadIdx.x];
    const int o = g * 128 + threadIdx.x;
    ksrc[o] = src[e]; kdst[o] = dst[e]; ktyp[o] = et[e];
  }
}

// ---------------------------------------------------------------- CSR build
__global__ void csr_count(const int* __restrict__ ksrc, const int* __restrict__ kdst,
                          int* __restrict__ counts)
{
  const int i = blockIdx.x * 256 + threadIdx.x;
  if (i >= NGRAPH * KKEEP) return;
  atomicAdd(&counts[kdst[i]], 1);
  atomicAdd(&counts[ksrc[i]], 1);
}

__global__ void csr_offsets(const int* __restrict__ counts, int* __restrict__ offs,
                            int* __restrict__ cursor)
{
  const int g = blockIdx.x, t = threadIdx.x;   // 128 threads
  __shared__ int s[128];
  const int mc = counts[g * 128 + t];
  s[t] = mc;
  __syncthreads();
  for (int dd = 1; dd < 128; dd <<= 1) {
    int v = (t >= dd) ? s[t - dd] : 0;
    __syncthreads();
    s[t] += v;
    __syncthreads();
  }
  const int o = g * 256 + (s[t] - mc);
  offs[g * 128 + t] = o;
  cursor[g * 128 + t] = o;
}

__global__ void csr_fill(const int* __restrict__ ksrc, const int* __restrict__ kdst,
                         const int* __restrict__ ktyp, int* __restrict__ cursor,
                         int* __restrict__ nsrc, int* __restrict__ ntyp)
{
  const int i = blockIdx.x * 256 + threadIdx.x;
  if (i >= NGRAPH * KKEEP) return;
  const int s = ksrc[i], d = kdst[i], t = ktyp[i];
  int p = atomicAdd(&cursor[d], 1); nsrc[p] = s; ntyp[p] = t;
  int q = atomicAdd(&cursor[s], 1); nsrc[q] = d; ntyp[q] = t;
}

// ---------------------------------------------------------------- selected layer-0 agg
// xw0 layout: [5][NNODES][256] bf16 (z=0 root, z=1+r relation transforms).

// Initial branch (ring graph): rows g*5 + {0:node0, o:node 128-o (o=1..4)}.
__global__ void agg_struct_sel(const bf16_t* __restrict__ xw0, const int* __restrict__ et,
                               const float* __restrict__ conv_b, bf16_t* __restrict__ h1g)
{
  const int wid = threadIdx.x >> 6, lane = threadIdx.x & 63;
  const int row = blockIdx.x * 4 + wid;         // 0..1279
  const int g = row / 5, slot = row % 5;
  const int d = (slot == 0) ? 0 : (128 - slot);
  const int n = g * 128 + d;
  const int c = lane * 4;
  int rt[4], si[4];
  #pragma unroll
  for (int oo = 0; oo < 4; ++oo) {
    const int i = (d - oo - 1 + 128) & 127;
    rt[oo] = et[g * 512 + oo * 128 + i];
    si[oo] = g * 128 + i;
  }
  const float4 cb = *(const float4*)(conv_b + c);
  bf16x4 rv = *(const bf16x4*)(xw0 + (long)n * 256 + c);
  float acc[4] = { (float)rv[0] + cb.x, (float)rv[1] + cb.y,
                   (float)rv[2] + cb.z, (float)rv[3] + cb.w };
  float s0[4] = {0,0,0,0}, s1[4] = {0,0,0,0}, s2[4] = {0,0,0,0}, s3[4] = {0,0,0,0};
  int d0 = 0, d1 = 0, d2 = 0, d3 = 0;
  #pragma unroll
  for (int oo = 0; oo < 4; ++oo) {
    const int t = rt[oo];
    bf16x4 w = *(const bf16x4*)(xw0 + ((long)(t + 1) * NNODES + si[oo]) * 256 + c);
    if (t == 0)      { d0++; for (int j = 0; j < 4; ++j) s0[j] += (float)w[j]; }
    else if (t == 1) { d1++; for (int j = 0; j < 4; ++j) s1[j] += (float)w[j]; }
    else if (t == 2) { d2++; for (int j = 0; j < 4; ++j) s2[j] += (float)w[j]; }
    else             { d3++; for (int j = 0; j < 4; ++j) s3[j] += (float)w[j]; }
  }
  if (d0) { float r = 1.f / d0; for (int j = 0; j < 4; ++j) acc[j] += s0[j] * r; }
  if (d1) { float r = 1.f / d1; for (int j = 0; j < 4; ++j) acc[j] += s1[j] * r; }
  if (d2) { float r = 1.f / d2; for (int j = 0; j < 4; ++j) acc[j] += s2[j] * r; }
  if (d3) { float r = 1.f / d3; for (int j = 0; j < 4; ++j) acc[j] += s3[j] * r; }
  bf16x4 ov; for (int j = 0; j < 4; ++j) ov[j] = (bf16_t)acc[j];
  *(bf16x4*)(h1g + (long)row * 256 + c) = ov;
}

// Learned branch (CSR graph): rows 1280 + g*16 + {0:ptr, 1+j: nsrc[off0+j]}.
__global__ void agg_csr_sel(const bf16_t* __restrict__ xw0, const int* __restrict__ offs,
                            const int* __restrict__ cnts, const int* __restrict__ nsrc,
                            const int* __restrict__ ntyp, const float* __restrict__ conv_b,
                            bf16_t* __restrict__ h1g)
{
  const int wid = threadIdx.x >> 6, lane = threadIdx.x & 63;
  const int idx = blockIdx.x * 4 + wid;         // 0..4095
  const int g = idx >> 4, slot = idx & 15;
  const int off0 = offs[g * 128], cnt0 = cnts[g * 128];
  if (slot > cnt0) return;                      // slot 0 = root, 1..cnt0 = srcs
  const int v = (slot == 0) ? g * 128 : nsrc[off0 + slot - 1];
  const int row = 1280 + idx;
  const int offv = offs[v], cntv = cnts[v];
  const int c = lane * 4;
  const float4 cb = *(const float4*)(conv_b + c);
  bf16x4 rv = *(const bf16x4*)(xw0 + (long)v * 256 + c);
  float acc[4] = { (float)rv[0] + cb.x, (float)rv[1] + cb.y,
                   (float)rv[2] + cb.z, (float)rv[3] + cb.w };
  float s0[4] = {0,0,0,0}, s1[4] = {0,0,0,0}, s2[4] = {0,0,0,0}, s3[4] = {0,0,0,0};
  int d0 = 0, d1 = 0, d2 = 0, d3 = 0;
  for (int j = 0; j < cntv; ++j) {
    const int t = ntyp[offv + j];
    const int sv = nsrc[offv + j];
    bf16x4 w = *(const bf16x4*)(xw0 + ((long)(t + 1) * NNODES + sv) * 256 + c);
    if (t == 0)      { d0++; for (int q = 0; q < 4; ++q) s0[q] += (float)w[q]; }
    else if (t == 1) { d1++; for (int q = 0; q < 4; ++q) s1[q] += (float)w[q]; }
    else if (t == 2) { d2++; for (int q = 0; q < 4; ++q) s2[q] += (float)w[q]; }
    else             { d3++; for (int q = 0; q < 4; ++q) s3[q] += (float)w[q]; }
  }
  if (d0) { float r = 1.f / d0; for (int q = 0; q < 4; ++q) acc[q] += s0[q] * r; }
  if (d1) { float r = 1.f / d1; for (int q = 0; q < 4; ++q) acc[q] += s1[q] * r; }
  if (d2) { float r = 1.f / d2; for (int q = 0; q < 4; ++q) acc[q] += s2[q] * r; }
  if (d3) { float r = 1.f / d3; for (int q = 0; q < 4; ++q) acc[q] += s3[q] * r; }
  bf16x4 ov; for (int q = 0; q < 4; ++q) ov[q] = (bf16_t)acc[q];
  *(bf16x4*)(h1g + (long)row * 256 + c) = ov;
}

// ---------------------------------------------------------------- final (layer-1) agg at ptr
// xw1 layout: [5][M1][256] bf16 over the gathered rows.
__global__ void fagg_init(const bf16_t* __restrict__ xw1, const int* __restrict__ et,
                          const float* __restrict__ conv_b1, float* __restrict__ h2I)
{
  const int wid = threadIdx.x >> 6, lane = threadIdx.x & 63;
  const int g = blockIdx.x * 4 + wid;           // 0..255
  const int base = g * 5;
  const int c = lane * 4;
  const float4 cb = *(const float4*)(conv_b1 + c);
  bf16x4 rv = *(const bf16x4*)(xw1 + (long)base * 256 + c);
  float acc[4] = { (float)rv[0] + cb.x, (float)rv[1] + cb.y,
                   (float)rv[2] + cb.z, (float)rv[3] + cb.w };
  float s0[4] = {0,0,0,0}, s1[4] = {0,0,0,0}, s2[4] = {0,0,0,0}, s3[4] = {0,0,0,0};
  int d0 = 0, d1 = 0, d2 = 0, d3 = 0;
  #pragma unroll
  for (int o = 1; o <= 4; ++o) {
    const int t = et[g * 512 + (o - 1) * 128 + (128 - o)];
    bf16x4 w = *(const bf16x4*)(xw1 + ((long)(t + 1) * M1 + base + o) * 256 + c);
    if (t == 0)      { d0++; for (int q = 0; q < 4; ++q) s0[q] += (float)w[q]; }
    else if (t == 1) { d1++; for (int q = 0; q < 4; ++q) s1[q] += (float)w[q]; }
    else if (t == 2) { d2++; for (int q = 0; q < 4; ++q) s2[q] += (float)w[q]; }
    else             { d3++; for (int q = 0; q < 4; ++q) s3[q] += (float)w[q]; }
  }
  if (d0) { float r = 1.f / d0; for (int q = 0; q < 4; ++q) acc[q] += s0[q] * r; }
  if (d1) { float r = 1.f / d1; for (int q = 0; q < 4; ++q) acc[q] += s1[q] * r; }
  if (d2) { float r = 1.f / d2; for (int q = 0; q < 4; ++q) acc[q] += s2[q] * r; }
  if (d3) { float r = 1.f / d3; for (int q = 0; q < 4; ++q) acc[q] += s3[q] * r; }
  *(float4*)(h2I + (long)g * 256 + c) = make_float4(acc[0], acc[1], acc[2], acc[3]);
}

__global__ void fagg_learn(const bf16_t* __restrict__ xw1, const int* __restrict__ offs,
                           const int* __restrict__ cnts, const int* __restrict__ ntyp,
                           const float* __restrict__ conv_b1, float* __restrict__ h2L)
{
  const int wid = threadIdx.x >> 6, lane = threadIdx.x & 63;
  const int g = blockIdx.x * 4 + wid;           // 0..255
  const int base = 1280 + g * 16;
  const int off0 = offs[g * 128], cnt0 = cnts[g * 128];
  const int c = lane * 4;
  const float4 cb = *(const float4*)(conv_b1 + c);
  bf16x4 rv = *(const bf16x4*)(xw1 + (long)base * 256 + c);
  float acc[4] = { (float)rv[0] + cb.x, (float)rv[1] + cb.y,
                   (float)rv[2] + cb.z, (float)rv[3] + cb.w };
  float s0[4] = {0,0,0,0}, s1[4] = {0,0,0,0}, s2[4] = {0,0,0,0}, s3[4] = {0,0,0,0};
  int d0 = 0, d1 = 0, d2 = 0, d3 = 0;
  for (int j = 0; j < cnt0; ++j) {
    const int t = ntyp[off0 + j];
    bf16x4 w = *(const bf16x4*)(xw1 + ((long)(t + 1) * M1 + base + 1 + j) * 256 + c);
    if (t == 0)      { d0++; for (int q = 0; q < 4; ++q) s0[q] += (float)w[q]; }
    else if (t == 1) { d1++; for (int q = 0; q < 4; ++q) s1[q] += (float)w[q]; }
    else if (t == 2) { d2++; for (int q = 0; q < 4; ++q) s2[q] += (float)w[q]; }
    else             { d3++; for (int q = 0; q < 4; ++q) s3[q] += (float)w[q]; }
  }
  if (d0) { float r = 1.f / d0; for (int q = 0; q < 4; ++q) acc[q] += s0[q] * r; }
  if (d1) { float r = 1.f / d1; for (int q = 0; q < 4; ++q) acc[q] += s1[q] * r; }
  if (d2) { float r = 1.f / d2; for (int q = 0; q < 4; ++q) acc[q] += s2[q] * r; }
  if (d3) { float r = 1.f / d3; for (int q = 0; q < 4; ++q) acc[q] += s3[q] * r; }
  *(float4*)(h2L + (long)g * 256 + c) = make_float4(acc[0], acc[1], acc[2], acc[3]);
}

// ---------------------------------------------------------------- classifier head
__global__ void classifier_kernel(const float* __restrict__ h2I, const float* __restrict__ h2L,
                                  const float* __restrict__ w1, const float* __restrict__ b1,
                                  const float* __restrict__ w2, const float* __restrict__ b2,
                                  const int* __restrict__ y, float* __restrict__ out,
                                  float* __restrict__ logp)
{
  const int g = blockIdx.x, t = threadIdx.x;
  __shared__ float rep[512];
  __shared__ float hid[256];
  __shared__ float lg[4];
  rep[t] = h2I[g * 256 + t];
  rep[256 + t] = h2L[g * 256 + t];
  __syncthreads();
  float a = b1[t];
  for (int i = 0; i < 512; ++i) a += rep[i] * w1[i * 256 + t];
  hid[t] = a > 0.f ? a : 0.01f * a;
  __syncthreads();
  if (t < 4) {
    float s = b2[t];
    for (int j = 0; j < 256; ++j) s += hid[j] * w2[j * 4 + t];
    lg[t] = s;
    out[g * 4 + t] = s;
  }
  __syncthreads();
  if (t == 0) {
    float m = fmaxf(fmaxf(lg[0], lg[1]), fmaxf(lg[2], lg[3]));
    float se = expf(lg[0] - m) + expf(lg[1] - m) + expf(lg[2] - m) + expf(lg[3] - m);
    logp[g] = lg[y[g]] - (m + logf(se));
  }
}

__global__ void finalize_kernel(const float* __restrict__ logp, const int* __restrict__ y,
                                float* __restrict__ out)
{
  __shared__ float s[256];
  const int t = threadIdx.x;
  s[t] = logp[t];
  __syncthreads();
  for (int d = 128; d > 0; d >>= 1) {
    if (t < d) s[t] += s[t + d];
    __syncthreads();
  }
  if (t == 0) out[1024] = -s[0] / 256.f;
  out[1025 + t] = (float)y[t];
}

// ---------------------------------------------------------------- launcher
extern "C" void kernel_launch(void* const* d_in, const int* in_sizes, int n_in,
                              void* d_out, int out_size, void* d_ws, size_t ws_size,
                              hipStream_t stream)
{
  (void)in_sizes; (void)n_in; (void)out_size; (void)ws_size;
  const float* x      = (const float*)d_in[0];
  const int*   ei     = (const int*)d_in[1];
  const int*   et     = (const int*)d_in[2];
  const int*   y      = (const int*)d_in[3];
  const float* gen_w  = (const float*)d_in[4];
  const float* gen_b  = (const float*)d_in[5];
  const float* att_w1 = (const float*)d_in[6];
  const float* att_b1 = (const float*)d_in[7];
  const float* att_w2 = (const float*)d_in[8];
  const float* att_b2 = (const float*)d_in[9];
  const float* in_w   = (const float*)d_in[10];
  const float* in_b   = (const float*)d_in[11];
  const float* rel_w  = (const float*)d_in[12];
  const float* root_w = (const float*)d_in[13];
  const float* conv_b = (const float*)d_in[14];
  const float* cls_w1 = (const float*)d_in[15];
  const float* cls_b1 = (const float*)d_in[16];
  const float* cls_w2 = (const float*)d_in[17];
  const float* cls_b2 = (const float*)d_in[18];
  const int* src = ei;
  const int* dst = ei + NEDGE;

  char* ws = (char*)d_ws;
  // Region 0 (time-shared, sequential lifetimes):
  //   AB (134.2MB) -> xw0 (83.9MB); region0 = 134.2MB. x consumed directly (fused cast).
  size_t off = 134217728;
  const size_t oBIG = 0;
  auto alloc = [&](size_t bytes) { size_t r = off; off += (bytes + 255) & ~(size_t)255; return r; };
  const size_t oH0  = alloc((size_t)NNODES * 256 * 2);
  const size_t oHG  = alloc((size_t)NNODES * 256 * 2);   // adjacent to oH0 (N-batched GEMM)
  const size_t oH1G = alloc((size_t)M1 * 256 * 2);
  const size_t oXW1 = alloc((size_t)5 * M1 * 256 * 2);
  const size_t oSC  = alloc((size_t)NEDGE * 4);
  const size_t oKS  = alloc((size_t)NGRAPH * KKEEP * 4);
  const size_t oKD  = alloc((size_t)NGRAPH * KKEEP * 4);
  const size_t oKT  = alloc((size_t)NGRAPH * KKEEP * 4);
  const size_t oCNT = alloc((size_t)NNODES * 4);
  const size_t oOFF = alloc((size_t)NNODES * 4);
  const size_t oCUR = alloc((size_t)NNODES * 4);
  const size_t oNS  = alloc((size_t)2 * NGRAPH * KKEEP * 4);
  const size_t oNT  = alloc((size_t)2 * NGRAPH * KKEEP * 4);
  const size_t oWBF = alloc((size_t)2 * 256 * 768 * 2);
  const size_t oATT = alloc((size_t)2 * 1024 * 256 * 2);
  const size_t oLW  = alloc((size_t)2 * 5 * 256 * 256 * 2);
  const size_t oBIA = alloc(512 * 4);
  const size_t oH2I = alloc((size_t)NGRAPH * 256 * 4);
  const size_t oH2L = alloc((size_t)NGRAPH * 256 * 4);
  const size_t oLP  = alloc((size_t)NGRAPH * 4);

  bf16_t* AB   = (bf16_t*)(ws + oBIG);   // [2][32768][1024]
  bf16_t* xw0  = (bf16_t*)(ws + oBIG);   // [5][NNODES][256]
  bf16_t* h0   = (bf16_t*)(ws + oH0);
  bf16_t* hg   = (bf16_t*)(ws + oHG);
  bf16_t* h1g  = (bf16_t*)(ws + oH1G);   // [M1][256] gathered layer-1 input
  bf16_t* xw1  = (bf16_t*)(ws + oXW1);   // [5][M1][256]
  bf16_t* wbf  = (bf16_t*)(ws + oWBF);
  bf16_t* attT = (bf16_t*)(ws + oATT);
  bf16_t* lw   = (bf16_t*)(ws + oLW);
  float*  bias = (float*)(ws + oBIA);

  // 1. weight prep
  prep_kernel<<<6146, 256, 0, stream>>>(in_w, gen_w, att_w1, rel_w, root_w, in_b, gen_b,
                                        wbf, attT, lw, bias);

  // 2. h0 = leaky(x@in_w+b), hg = leaky(x@gen_w+b): fused f32 cast, Ntot=512, slabs of 256
  gemm_bt2<1, true, true><<<dim3(256, 2), 512, 0, stream>>>(
      (const void*)x, wbf, bias, h0, NNODES, 768, 8, 8388608L);

  // 3. A/B node factors: Ntot=2048, slabs of 1024; then per-edge scores (structured)
  gemm_bt2<0, false, false><<<dim3(256, 8), 512, 0, stream>>>(
      (const void*)hg, attT, nullptr, AB, NNODES, 256, 10, 33554432L);
  score_kernel<<<8192, 256, 0, stream>>>(AB, AB + 33554432L, att_b1, att_w2,
                                         att_b2, (float*)(ws + oSC));

  // 4. per-graph top-k and learned-graph CSR (symmetrized)
  topk_kernel<<<NGRAPH, 256, 0, stream>>>((const float*)(ws + oSC), src, dst, et,
                                          (int*)(ws + oKS), (int*)(ws + oKD), (int*)(ws + oKT));
  hipMemsetAsync(ws + oCNT, 0, (size_t)NNODES * 4, stream);
  csr_count<<<128, 256, 0, stream>>>((const int*)(ws + oKS), (const int*)(ws + oKD), (int*)(ws + oCNT));
  csr_offsets<<<NGRAPH, 128, 0, stream>>>((const int*)(ws + oCNT), (int*)(ws + oOFF), (int*)(ws + oCUR));
  csr_fill<<<128, 256, 0, stream>>>((const int*)(ws + oKS), (const int*)(ws + oKD),
                                    (const int*)(ws + oKT), (int*)(ws + oCUR),
                                    (int*)(ws + oNS), (int*)(ws + oNT));

  // 5. layer-0 transforms: Ntot=1280 (root + 4 relations), slabs of 256
  gemm_bt2<0, false, false><<<dim3(256, 5), 512, 0, stream>>>(
      (const void*)h0, lw, nullptr, xw0, NNODES, 256, 8, 8388608L);

  // 6. layer-0 aggregation ONLY at the <=21 nodes/graph feeding the readout
  agg_struct_sel<<<320, 256, 0, stream>>>(xw0, et, conv_b, h1g);
  agg_csr_sel<<<1024, 256, 0, stream>>>(xw0, (const int*)(ws + oOFF), (const int*)(ws + oCNT),
                                        (const int*)(ws + oNS), (const int*)(ws + oNT),
                                        conv_b, h1g);

  // 7. layer-1 transforms on gathered rows (M=5376, Ntot=1280)
  gemm_bt2<0, false, false><<<dim3(42, 5), 512, 0, stream>>>(
      (const void*)h1g, lw + 5 * 65536, nullptr, xw1, M1, 256, 8, (long)PLANE1);

  // 8. layer-1 aggregation at ptr nodes
  fagg_init<<<64, 256, 0, stream>>>(xw1, et, conv_b + 256, (float*)(ws + oH2I));
  fagg_learn<<<64, 256, 0, stream>>>(xw1, (const int*)(ws + oOFF), (const int*)(ws + oCNT),
                                     (const int*)(ws + oNT), conv_b + 256, (float*)(ws + oH2L));

  // 9. classifier + loss + y passthrough
  classifier_kernel<<<NGRAPH, 256, 0, stream>>>((const float*)(ws + oH2I), (const float*)(ws + oH2L),
                                                cls_w1, cls_b1, cls_w2, cls_b2, y,
                                                (float*)d_out, (float*)(ws + oLP));
  finalize_kernel<<<1, 256, 0, stream>>>((const float*)(ws + oLP), y, (float*)d_out);
}